// Round 10
// baseline (435.145 us; speedup 1.0000x reference)
//
#include <hip/hip_runtime.h>
#include <math.h>

#define CC   128
#define HH   16
#define WW   16
#define BB   32
#define VV   8192
#define NELEM (BB*CC*HH*WW)   // 1,048,576

typedef short short8 __attribute__((ext_vector_type(8)));
typedef float floatx4 __attribute__((ext_vector_type(4)));

#define CSTR 136   // conv LDS row stride in bf16 elems (128 + 8 pad)

// address-space helpers for global_load_lds
typedef __attribute__((address_space(1))) void as1_void;
typedef __attribute__((address_space(3))) void as3_void;

__device__ __forceinline__ void gl_lds16(const void* g, void* l) {
    // LDS dest is wave-uniform base; HW adds lane*16. Global src is per-lane.
    __builtin_amdgcn_global_load_lds((as1_void*)g, (as3_void*)l, 16, 0, 0);
}

// ---------------- hi/lo bf16 split pack (RNE both) ----------------
__device__ __forceinline__ uint32_t pack_hilo(float x) {
    uint32_t u = __float_as_uint(x);
    uint32_t hb = (u + 0x7fffu + ((u >> 16) & 1u)) & 0xffff0000u;
    float hf = __uint_as_float(hb);
    float lo = x - hf;
    uint32_t ul = __float_as_uint(lo);
    uint32_t lb = ((ul + 0x7fffu + ((ul >> 16) & 1u)) >> 16) & 0xffffu;
    return hb | lb;
}

// ---------------- e_sq + codebook hi/lo plane split + lacc zero ----------------
// 131072 threads: 16 per codebook row.
// ephi/eplo are written in MFMA-fragment order per 128-row vtile:
//   elem (v, c): vt=v>>7, vr=v&127, vh=vr>>6, tj=(vr>>4)&3, l15=vr&15,
//                kc=c>>5, quad=(c>>3)&3, e=c&7
//   off = vt*16384 + ((kc*8 + vh*4 + tj)*64 + quad*16 + l15)*8 + e
// A 64-v half-tile (vt, half) is the 16 chunks {kc*8 + half*4 + g16}, each 1KB.
__global__ void esq_pack(const float* __restrict__ emb, float* __restrict__ esq,
                         short* __restrict__ ephi, short* __restrict__ eplo,
                         float* __restrict__ lacc) {
    int t = blockIdx.x * 256 + threadIdx.x;
    int v = t >> 4, g = t & 15;
    const float* row = emb + (size_t)v * CC + g * 8;
    float4 a = *(const float4*)row;
    float4 b = *(const float4*)(row + 4);
    float s = a.x*a.x + a.y*a.y + a.z*a.z + a.w*a.w
            + b.x*b.x + b.y*b.y + b.z*b.z + b.w*b.w;
    s += __shfl_xor(s, 1, 64);
    s += __shfl_xor(s, 2, 64);
    s += __shfl_xor(s, 4, 64);
    s += __shfl_xor(s, 8, 64);
    if (g == 0) esq[v] = s;
    float vals[8] = {a.x, a.y, a.z, a.w, b.x, b.y, b.z, b.w};
    short hs[8], ls[8];
#pragma unroll
    for (int j = 0; j < 8; j++) {
        uint32_t u = pack_hilo(vals[j]);
        hs[j] = (short)(u >> 16);
        ls[j] = (short)(u & 0xffffu);
    }
    int vt = v >> 7, vr = v & 127;
    int vh = vr >> 6, tj = (vr >> 4) & 3, r15 = vr & 15;
    int kc = g >> 2, quad = g & 3;
    size_t off = (size_t)vt * 16384 + (size_t)((kc * 8 + vh * 4 + tj) * 64 + quad * 16 + r15) * 8;
    *(short8*)(ephi + off) = *(short8*)hs;
    *(short8*)(eplo + off) = *(short8*)ls;
    if (t == 0) lacc[0] = 0.f;
}

// ---------------- pre-transpose + split conv weights: Wt[kphi][kk][cout][cin] ----------------
__global__ void prepack_w(const float* __restrict__ pw, short* __restrict__ Whi,
                          short* __restrict__ Wlo) {
    int id = blockIdx.x * 256 + threadIdx.x;      // 65536 = 4*128*128
    int ci = id & 127, cout = (id >> 7) & 127, kp = id >> 14;
    const float* src = pw + ((size_t)(kp * CC + cout) * CC + ci) * 9;
#pragma unroll
    for (int kk = 0; kk < 9; kk++) {
        uint32_t u = pack_hilo(src[kk]);
        size_t o = ((size_t)(kp * 9 + kk) * CC + cout) * CC + ci;
        Whi[o] = (short)(u >> 16);
        Wlo[o] = (short)(u & 0xffffu);
    }
}

// ---------------- pooled residual (f - f_hat) -> hi/lo planes ----------------
template <bool FIRSTP>
__global__ void pool_pack(const float* __restrict__ f, const float* __restrict__ fh,
                          short* __restrict__ rh, short* __restrict__ rl, int pn) {
    int id = blockIdx.x * 256 + threadIdx.x;
    int c = id % CC;
    int n = id / CC;
    int px = n % pn;
    int py = (n / pn) % pn;
    int b  = n / (pn * pn);
    int s  = HH / pn;
    size_t o = (((size_t)b * CC + c) * HH + py * s) * WW + px * s;
    float acc = 0.f;
    for (int dy = 0; dy < s; dy++)
        for (int dx = 0; dx < s; dx++)
            acc += FIRSTP ? f[o + dy * WW + dx] : (f[o + dy * WW + dx] - fh[o + dy * WW + dx]);
    uint32_t u = pack_hilo(acc * (1.f / (float)(s * s)));
    rh[id] = (short)(u >> 16);
    rl[id] = (short)(u & 0xffffu);
}

// ---------------- MFMA distance v14: v12 geometry + single-barrier 2-phase loop ----------------
// block 512 = 8 waves: qq = wave&3 (32-q quarter), vh = wave>>2 (32-v half of the 64-v step).
// R7(v12) was barrier-bound: 2 barriers/step phase-lock the 8 waves (read-phase and
// MFMA-phase serialize on the CU pipes -> MfmaUtil stuck at 45%). This round adopts the
// guide's minimal 2-phase schedule: STAGE(s+1) -> compute(s) -> vmcnt(0) -> ONE barrier.
// Safety: buf[cur^1] was last read in step s-1; every wave's ds_reads complete (lgkmcnt)
// before its MFMAs, hence before it reaches the end-of-step barrier -> STAGE after that
// barrier cannot race. Drain lands after the ~1240-cyc compute phase (prefetch overlap
// preserved); min-update VALU covers the drain. Numerics bit-identical to v12.
__global__ __launch_bounds__(512, 4)
void dist_mfma(const short* __restrict__ rphi, const short* __restrict__ rplo,
               const short* __restrict__ ephi, const short* __restrict__ eplo,
               const float* __restrict__ esq,
               float* __restrict__ pbD, int* __restrict__ pbI,
               int N, int vtPB) {
    __shared__ short Bs[2][2][8192];       // [dbuf][hi/lo][64-v step, chunks kc*4+g16]
    __shared__ float EsqL[1024];           // esq slice (<= 8 vtiles * 128)

    const int tid  = threadIdx.x;
    const int wave = tid >> 6, ln = tid & 63;
    const int quad = ln >> 4, l15 = ln & 15;
    const int qq = wave & 3, vh = wave >> 2;
    const int qb0 = blockIdx.x * 128;
    const int vslices = gridDim.y;
    const int vt0 = blockIdx.y * vtPB;     // in 128-v vtile units
    const int nsteps = vtPB * 2;           // 64-v steps

// stage 64-v half-tile (vt0+(s>>1), s&1): 16 chunks of 1KB per plane, 2/plane/wave
#define STAGE_STEP(buf_, s_) do {                                                    \
        const int vt_ = vt0 + ((s_) >> 1);                                           \
        const int hf_ = (s_) & 1;                                                    \
        _Pragma("unroll")                                                            \
        for (int i_ = 0; i_ < 2; i_++) {                                             \
            const int ck_ = wave * 2 + i_;                                           \
            const int kc_ = ck_ >> 2, g_ = ck_ & 3;                                  \
            const size_t so_ = (size_t)vt_ * 32768 +                                 \
                               (size_t)(kc_ * 8 + hf_ * 4 + g_) * 1024;              \
            gl_lds16((const char*)ephi + so_ + ln * 16, (char*)&Bs[(buf_)][0][0] + ck_ * 1024); \
            gl_lds16((const char*)eplo + so_ + ln * 16, (char*)&Bs[(buf_)][1][0] + ck_ * 1024); \
        } } while (0)

    // prologue: stage step 0, the esq slice, and A frags; full drain + barrier once
    STAGE_STEP(0, 0);
    {
        int echunks = (vtPB * 512 + 1023) >> 10;   // 1KB chunks of the esq slice (bytes)
        if (wave < echunks)
            gl_lds16((const char*)(esq + vt0 * 128) + wave * 1024 + ln * 16,
                     (char*)EsqL + wave * 1024);
    }

    // A fragments loaded once: 32 q per wave (rows may exceed N: garbage but finite;
    // outputs guarded). 16 short8 = 64 VGPRs.
    short8 av[2][4], aw[2][4];
#pragma unroll
    for (int ti = 0; ti < 2; ti++) {
        const size_t arow = (size_t)(qb0 + qq * 32 + ti * 16 + l15) * CC + quad * 8;
#pragma unroll
        for (int kc = 0; kc < 4; kc++) {
            av[ti][kc] = *(const short8*)(rphi + arow + kc * 32);
            aw[ti][kc] = *(const short8*)(rplo + arow + kc * 32);
        }
    }
    __builtin_amdgcn_sched_barrier(0);
    asm volatile("s_waitcnt vmcnt(0)" ::: "memory");   // stage0 + esq + A resident
    __builtin_amdgcn_sched_barrier(0);
    __builtin_amdgcn_s_barrier();
    __builtin_amdgcn_sched_barrier(0);

    float bD[2][4];
    int   bI[2][4];
#pragma unroll
    for (int ti = 0; ti < 2; ti++)
#pragma unroll
        for (int r = 0; r < 4; r++) { bD[ti][r] = INFINITY; bI[ti][r] = 0; }

    int cur = 0;
    for (int s = 0; s < nsteps; s++) {
        // issue next-step stage first; it lands during this step's compute
        if (s + 1 < nsteps) STAGE_STEP(cur ^ 1, s + 1);
        __builtin_amdgcn_sched_barrier(0);   // pin stage issue before compute

        floatx4 acc[2][2];
        floatx4 z = {0.f, 0.f, 0.f, 0.f};
#pragma unroll
        for (int ti = 0; ti < 2; ti++)
#pragma unroll
            for (int tj = 0; tj < 2; tj++) acc[ti][tj] = z;

        // fragment reads: chunk (kc*4 + vh*2 + tj)*1024B + lane*16B -> conflict-free linear
        const short* Bh = &Bs[cur][0][0];
        const short* Bl = &Bs[cur][1][0];
#pragma unroll
        for (int kc = 0; kc < 4; kc++) {
            short8 bh[2], bl[2];
#pragma unroll
            for (int tj = 0; tj < 2; tj++) {
                const int ck = kc * 4 + vh * 2 + tj;
                bh[tj] = *(const short8*)(Bh + ck * 512 + ln * 8);
                bl[tj] = *(const short8*)(Bl + ck * 512 + ln * 8);
            }
            // pass-major within kc: 4 runs of 4 independent MFMAs.
            // Per-acc order per kc: av*bh, aw*bh, av*bl, aw*bl -> bit-identical.
#pragma unroll
            for (int tj = 0; tj < 2; tj++)
#pragma unroll
                for (int ti = 0; ti < 2; ti++)
                    acc[ti][tj] = __builtin_amdgcn_mfma_f32_16x16x32_bf16(av[ti][kc], bh[tj], acc[ti][tj], 0, 0, 0);
#pragma unroll
            for (int tj = 0; tj < 2; tj++)
#pragma unroll
                for (int ti = 0; ti < 2; ti++)
                    acc[ti][tj] = __builtin_amdgcn_mfma_f32_16x16x32_bf16(aw[ti][kc], bh[tj], acc[ti][tj], 0, 0, 0);
#pragma unroll
            for (int tj = 0; tj < 2; tj++)
#pragma unroll
                for (int ti = 0; ti < 2; ti++)
                    acc[ti][tj] = __builtin_amdgcn_mfma_f32_16x16x32_bf16(av[ti][kc], bl[tj], acc[ti][tj], 0, 0, 0);
#pragma unroll
            for (int tj = 0; tj < 2; tj++)
#pragma unroll
                for (int ti = 0; ti < 2; ti++)
                    acc[ti][tj] = __builtin_amdgcn_mfma_f32_16x16x32_bf16(aw[ti][kc], bl[tj], acc[ti][tj], 0, 0, 0);
        }

        // dist = esq - 2*dot; esq from LDS (lgkmcnt only).
        // v ascending over s/tj per lane -> strict < keeps first min
        const int v0 = (vt0 + (s >> 1)) * 128 + (s & 1) * 64;
#pragma unroll
        for (int tj = 0; tj < 2; tj++) {
            int vg = v0 + vh * 32 + tj * 16 + l15;
            float ev = EsqL[s * 64 + vh * 32 + tj * 16 + l15];
#pragma unroll
            for (int ti = 0; ti < 2; ti++)
#pragma unroll
                for (int r = 0; r < 4; r++) {
                    float d = fmaf(-2.f, acc[ti][tj][r], ev);
                    if (d < bD[ti][r]) { bD[ti][r] = d; bI[ti][r] = vg; }
                }
        }

        // single barrier per step: drain the in-flight stage (landed under compute),
        // then sync. After this barrier all waves are done reading buf[cur].
        __builtin_amdgcn_sched_barrier(0);
        asm volatile("s_waitcnt vmcnt(0)" ::: "memory");
        __builtin_amdgcn_sched_barrier(0);
        __builtin_amdgcn_s_barrier();
        __builtin_amdgcn_sched_barrier(0);
        cur ^= 1;
    }
#undef STAGE_STEP

    // cross-lane reduce within 16-lane groups (same q, different v), tie -> lower v
#pragma unroll
    for (int ti = 0; ti < 2; ti++)
#pragma unroll
        for (int r = 0; r < 4; r++) {
            float d = bD[ti][r];
            int   v = bI[ti][r];
#pragma unroll
            for (int m = 1; m <= 8; m <<= 1) {
                float od = __shfl_xor(d, m, 64);
                int   ov = __shfl_xor(v, m, 64);
                if (od < d || (od == d && ov < v)) { d = od; v = ov; }
            }
            if (l15 == 0) {
                int q = qb0 + qq * 32 + ti * 16 + quad * 4 + r;
                if (q < N) {
                    size_t o = (size_t)q * (vslices * 2) + blockIdx.y * 2 + vh;
                    pbD[o] = d;
                    pbI[o] = v;
                }
            }
        }
}

// ---------------- Keys cubic a=-0.5 (matches jax) ----------------
__device__ __forceinline__ float cubic_k(float x) {
    if (x <= 1.f) return (1.5f * x - 2.5f) * x * x + 1.f;
    if (x < 2.f)  return ((-0.5f * x + 2.5f) * x - 4.f) * x + 2.f;
    return 0.f;
}

// ---------------- fused argmin + upsample -> h planes ----------------
// grid = (32 b * 16 cig), 256 threads = pixel; 8 channels per thread.
// Partial-min merge over vsplit slices is parallel (all 256 threads + tree).
template <int PN>
__global__ __launch_bounds__(256)
void upsample_pack(const float* __restrict__ emb,
                   const float* __restrict__ pbD, const int* __restrict__ pbI, int vsplit,
                   short* __restrict__ hhi, short* __restrict__ hlo,
                   float* __restrict__ hfp) {
    const int t = threadIdx.x;
    const int x = t & 15, y = t >> 4;
    const int b = blockIdx.x >> 4;
    const int c0 = (blockIdx.x & 15) * 8;

    float val[8];

    if constexpr (PN == 16) {
        int q = b * 256 + t;
        float bd = pbD[(size_t)q * vsplit];
        int   bi = pbI[(size_t)q * vsplit];
        for (int j = 1; j < vsplit; j++) {
            float d  = pbD[(size_t)q * vsplit + j];
            int   i2 = pbI[(size_t)q * vsplit + j];
            if (d < bd || (d == bd && i2 < bi)) { bd = d; bi = i2; }
        }
        float4 v0 = *(const float4*)(emb + (size_t)bi * CC + c0);
        float4 v1 = *(const float4*)(emb + (size_t)bi * CC + c0 + 4);
        val[0]=v0.x; val[1]=v0.y; val[2]=v0.z; val[3]=v0.w;
        val[4]=v1.x; val[5]=v1.y; val[6]=v1.z; val[7]=v1.w;
    } else {
        constexpr int NQ = PN * PN;      // 1,4,16,64
        constexpr int KK = 256 / NQ;
        __shared__ int idxL[NQ];
        __shared__ float S[NQ][8];
        __shared__ float prd[256];
        __shared__ int   pri[256];

        // strided partial min: thread t covers query (t & NQ-1), slices t/NQ :: KK
        {
            const int qi = t & (NQ - 1);
            const int kk = t / NQ;
            float bd = INFINITY; int bi = 0;
            for (int j = kk; j < vsplit; j += KK) {
                float d  = pbD[(size_t)(b * NQ + qi) * vsplit + j];
                int   i2 = pbI[(size_t)(b * NQ + qi) * vsplit + j];
                if (d < bd || (d == bd && i2 < bi)) { bd = d; bi = i2; }
            }
            prd[t] = bd; pri[t] = bi;
        }
        __syncthreads();
        if (t < 64) {
            float d = prd[t]; int v = pri[t];
            for (int p = t + 64; p < 256; p += 64) {
                float d2 = prd[p]; int v2 = pri[p];
                if (d2 < d || (d2 == d && v2 < v)) { d = d2; v = v2; }
            }
#pragma unroll
            for (int m = NQ; m < 64; m <<= 1) {
                float d2 = __shfl_xor(d, m, 64);
                int   v2 = __shfl_xor(v, m, 64);
                if (d2 < d || (d2 == d && v2 < v)) { d = d2; v = v2; }
            }
            if (t < NQ) idxL[t] = v;
        }
        __syncthreads();
        if (t < NQ) {
            float4 v0 = *(const float4*)(emb + (size_t)idxL[t] * CC + c0);
            float4 v1 = *(const float4*)(emb + (size_t)idxL[t] * CC + c0 + 4);
            S[t][0]=v0.x; S[t][1]=v0.y; S[t][2]=v0.z; S[t][3]=v0.w;
            S[t][4]=v1.x; S[t][5]=v1.y; S[t][6]=v1.z; S[t][7]=v1.w;
        }
        __syncthreads();

        const float sc = (float)PN / 16.f;
        float sy = (y + 0.5f) * sc - 0.5f;
        float sx = (x + 0.5f) * sc - 0.5f;
        int iy0 = (int)floorf(sy) - 1;
        int ix0 = (int)floorf(sx) - 1;
        float wy[4], wx[4];
        float ssy = 0.f, ssx = 0.f;
#pragma unroll
        for (int k = 0; k < 4; k++) {
            int iy = iy0 + k, ix = ix0 + k;
            float a = (iy >= 0 && iy < PN) ? cubic_k(fabsf(sy - (float)iy)) : 0.f;
            float bb = (ix >= 0 && ix < PN) ? cubic_k(fabsf(sx - (float)ix)) : 0.f;
            wy[k] = a; ssy += a;
            wx[k] = bb; ssx += bb;
        }
        float ry = 1.f / ssy, rx = 1.f / ssx;
#pragma unroll
        for (int k = 0; k < 4; k++) { wy[k] *= ry; wx[k] *= rx; }

#pragma unroll
        for (int j = 0; j < 8; j++) val[j] = 0.f;
#pragma unroll
        for (int k4 = 0; k4 < 4; k4++) {
            int iy = iy0 + k4;
            if (iy < 0 || iy >= PN) continue;
#pragma unroll
            for (int j4 = 0; j4 < 4; j4++) {
                int ix = ix0 + j4;
                if (ix < 0 || ix >= PN) continue;
                float w = wy[k4] * wx[j4];
                const float* sp = S[iy * PN + ix];
#pragma unroll
                for (int j = 0; j < 8; j++) val[j] = fmaf(w, sp[j], val[j]);
            }
        }
    }

    short hs[8], ls[8];
#pragma unroll
    for (int j = 0; j < 8; j++) {
        uint32_t u = pack_hilo(val[j]);
        hs[j] = (short)(u >> 16);
        ls[j] = (short)(u & 0xffffu);
    }
    size_t ho = ((size_t)(b * 18 + y + 1) * 18 + (x + 1)) * CC + c0;
    *(short8*)(hhi + ho) = *(short8*)hs;
    *(short8*)(hlo + ho) = *(short8*)ls;
#pragma unroll
    for (int j = 0; j < 8; j++)
        hfp[((size_t)b * CC + c0 + j) * 256 + t] = val[j];
}

// ---------------- MFMA conv3x3: LDS-shared weights, K-split (R5 structure) ----------------
template <bool FIRST>
__global__ __launch_bounds__(256)
void conv_mfma(const short* __restrict__ Whi, const short* __restrict__ Wlo,
               const short* __restrict__ hhi, const short* __restrict__ hlo,
               const float* __restrict__ hfp, const float* __restrict__ pb,
               const float* __restrict__ f, float* __restrict__ f_hat,
               float* __restrict__ lacc, int kphi) {
    __shared__ short Bsh[64 * CSTR];
    __shared__ short Bsl[64 * CSTR];
    __shared__ float red[2][16][65];
    __shared__ float lred[2];

    const int t = threadIdx.x;
    const int wave = t >> 6, lane = t & 63;
    const int quad = lane >> 4, l15 = lane & 15;
    const int pxg = wave & 1, kh = wave >> 1;
    const int cH = blockIdx.x & 1;
    const int pc = blockIdx.x >> 1;
    const int b = pc >> 3;
    const int pxbase = (pc & 7) * 32;
    const int pa = pxbase + pxg * 16 + l15;
    const int ya = pa >> 4, xa = pa & 15;

    floatx4 acc[4];
    floatx4 z = {0.f, 0.f, 0.f, 0.f};
#pragma unroll
    for (int nt = 0; nt < 4; nt++) acc[nt] = z;

    for (int kk = 0; kk < 9; kk++) {
        __syncthreads();
        {
            const short* gh = Whi + ((size_t)(kphi * 9 + kk) * CC + cH * 64) * CC;
            const short* gl = Wlo + ((size_t)(kphi * 9 + kk) * CC + cH * 64) * CC;
#pragma unroll
            for (int i = 0; i < 4; i++) {
                int chunk = i * 256 + t;
                int row = chunk >> 4, col = (chunk & 15) * 8;
                *(short8*)&Bsh[row * CSTR + col] = *(const short8*)(gh + row * CC + col);
                *(short8*)&Bsl[row * CSTR + col] = *(const short8*)(gl + row * CC + col);
            }
        }
        __syncthreads();

        const int ky = kk / 3, kx = kk % 3;
        const size_t aoff = ((size_t)(b * 18 + ya + ky) * 18 + (xa + kx)) * CC + quad * 8;
#pragma unroll
        for (int i2 = 0; i2 < 2; i2++) {
            const int cic = kh * 2 + i2;
            short8 ah = *(const short8*)(hhi + aoff + cic * 32);
            short8 al = *(const short8*)(hlo + aoff + cic * 32);
#pragma unroll
            for (int nt = 0; nt < 4; nt++) {
                short8 bh = *(const short8*)&Bsh[(nt * 16 + l15) * CSTR + cic * 32 + quad * 8];
                short8 bl = *(const short8*)&Bsl[(nt * 16 + l15) * CSTR + cic * 32 + quad * 8];
                acc[nt] = __builtin_amdgcn_mfma_f32_16x16x32_bf16(ah, bh, acc[nt], 0, 0, 0);
                acc[nt] = __builtin_amdgcn_mfma_f32_16x16x32_bf16(al, bh, acc[nt], 0, 0, 0);
                acc[nt] = __builtin_amdgcn_mfma_f32_16x16x32_bf16(ah, bl, acc[nt], 0, 0, 0);
            }
        }
    }

    __syncthreads();
    if (kh == 1) {
#pragma unroll
        for (int nt = 0; nt < 4; nt++)
#pragma unroll
            for (int r = 0; r < 4; r++)
                red[pxg][quad * 4 + r][nt * 16 + l15] = acc[nt][r];
    }
    __syncthreads();

    if (kh == 0) {
        const int pe = pxbase + pxg * 16 + quad * 4;
        float lsum = 0.f;
#pragma unroll
        for (int nt = 0; nt < 4; nt++) {
            int cout = cH * 64 + nt * 16 + l15;
            float bias = pb[kphi * CC + cout];
            size_t gi = ((size_t)b * CC + cout) * 256 + pe;
            float4 h4  = *(const float4*)(hfp + gi);
            float4 f4  = *(const float4*)(f + gi);
            float4 fh4 = FIRST ? make_float4(0.f, 0.f, 0.f, 0.f) : *(const float4*)(f_hat + gi);
            float c0 = acc[nt][0] + red[pxg][quad * 4 + 0][nt * 16 + l15] + bias;
            float c1 = acc[nt][1] + red[pxg][quad * 4 + 1][nt * 16 + l15] + bias;
            float c2 = acc[nt][2] + red[pxg][quad * 4 + 2][nt * 16 + l15] + bias;
            float c3 = acc[nt][3] + red[pxg][quad * 4 + 3][nt * 16 + l15] + bias;
            float o0 = fh4.x + 0.5f * h4.x + 0.5f * c0;
            float o1 = fh4.y + 0.5f * h4.y + 0.5f * c1;
            float o2 = fh4.z + 0.5f * h4.z + 0.5f * c2;
            float o3 = fh4.w + 0.5f * h4.w + 0.5f * c3;
            *(float4*)(f_hat + gi) = make_float4(o0, o1, o2, o3);
            float d0 = o0 - f4.x, d1 = o1 - f4.y, d2 = o2 - f4.z, d3 = o3 - f4.w;
            lsum += d0*d0 + d1*d1 + d2*d2 + d3*d3;
        }
#pragma unroll
        for (int off = 32; off; off >>= 1) lsum += __shfl_down(lsum, off, 64);
        if (lane == 0) lred[pxg] = lsum;
    }
    __syncthreads();
    if (t == 0) atomicAdd(lacc, lred[0] + lred[1]);
}

__global__ void finalize_kernel(const float* __restrict__ lacc, float* __restrict__ out_loss) {
    *out_loss = lacc[0] * (0.25f / (float)NELEM);   // (1+BETA)/SN * sum of means
}

extern "C" void kernel_launch(void* const* d_in, const int* in_sizes, int n_in,
                              void* d_out, int out_size, void* d_ws, size_t ws_size,
                              hipStream_t stream) {
    const float* f   = (const float*)d_in[0];
    const float* emb = (const float*)d_in[1];
    const float* pw  = (const float*)d_in[2];
    const float* pb  = (const float*)d_in[3];
    float* out = (float*)d_out;

    uint32_t* w32 = (uint32_t*)d_ws;
    short* rphi = (short*)(w32);                    // 1,048,576 shorts
    short* rplo = (short*)(w32 + 524288);
    short* ephi = (short*)(w32 + 1048576);          // 1,048,576 shorts
    short* eplo = (short*)(w32 + 1572864);
    short* Whi  = (short*)(w32 + 2097152);          // 589,824 shorts
    short* Wlo  = (short*)(w32 + 2392064);
    short* hhi  = (short*)(w32 + 2686976);          // 1,327,104 shorts
    short* hlo  = (short*)(w32 + 3350528);
    float* hfp  = (float*)(w32 + 4014080);          // 1,048,576 f
    float* esq  = (float*)(w32 + 5062656);          // 8192
    float* pbD  = (float*)(w32 + 5070848);          // 262144
    int*   pbI  = (int*)  (w32 + 5332992);          // 262144
    float* lacc = (float*)(w32 + 5595136);          // 1

    // zero halos of h planes (hhi & hlo contiguous)
    hipMemsetAsync(hhi, 0, (size_t)2 * 1327104 * sizeof(short), stream);

    esq_pack<<<512, 256, 0, stream>>>(emb, esq, ephi, eplo, lacc);
    prepack_w<<<256, 256, 0, stream>>>(pw, Whi, Wlo);

    // mirror np.linspace(1/12, 11/12, 4) exactly in float64
    double start = 1.0 / 12.0;
    double stop  = 1.0 - 1.0 / 12.0;
    double step  = (stop - start) / 3.0;
    double ticks[4] = {start, 1.0 * step + start, 2.0 * step + start, stop};

    const int pns[5]    = {1, 2, 4, 8, 16};
    const int qb5[5]    = {1, 1, 4, 16, 64};        // ceil(N/128)
    const int vs5[5]    = {64, 64, 64, 32, 8};      // vslices (x vtPB x 128 = 8192)
    const int vtPB5[5]  = {1, 1, 1, 2, 8};          // 128-v vtiles per block

    for (int si = 0; si < 5; si++) {
        int pn = pns[si];
        int N  = BB * pn * pn;
        double tt = (double)si / 4.0;
        int kphi = 0;
        double bd = fabs(ticks[0] - tt);
        for (int i = 1; i < 4; i++) {
            double d = fabs(ticks[i] - tt);
            if (d < bd) { bd = d; kphi = i; }   // np.argmin: first occurrence
        }

        if (si == 0) pool_pack<true><<<(N * CC) / 256, 256, 0, stream>>>(f, out, rphi, rplo, pn);
        else         pool_pack<false><<<(N * CC) / 256, 256, 0, stream>>>(f, out, rphi, rplo, pn);

        dim3 dgrid(qb5[si], vs5[si]);
        dist_mfma<<<dgrid, 512, 0, stream>>>(rphi, rplo, ephi, eplo, esq, pbD, pbI, N, vtPB5[si]);

        int vsplit = vs5[si] * 2;
        switch (pn) {
            case 1:  upsample_pack<1><<<512, 256, 0, stream>>>(emb, pbD, pbI, vsplit, hhi, hlo, hfp); break;
            case 2:  upsample_pack<2><<<512, 256, 0, stream>>>(emb, pbD, pbI, vsplit, hhi, hlo, hfp); break;
            case 4:  upsample_pack<4><<<512, 256, 0, stream>>>(emb, pbD, pbI, vsplit, hhi, hlo, hfp); break;
            case 8:  upsample_pack<8><<<512, 256, 0, stream>>>(emb, pbD, pbI, vsplit, hhi, hlo, hfp); break;
            default: upsample_pack<16><<<512, 256, 0, stream>>>(emb, pbD, pbI, vsplit, hhi, hlo, hfp); break;
        }

        if (si == 0) conv_mfma<true><<<512, 256, 0, stream>>>(Whi, Wlo, hhi, hlo, hfp, pb, f, out, lacc, kphi);
        else         conv_mfma<false><<<512, 256, 0, stream>>>(Whi, Wlo, hhi, hlo, hfp, pb, f, out, lacc, kphi);
    }

    finalize_kernel<<<1, 1, 0, stream>>>(lacc, out + NELEM);
}

// Round 11
// 433.324 us; speedup vs baseline: 1.0042x; 1.0042x over previous
//
#include <hip/hip_runtime.h>
#include <math.h>

#define CC   128
#define HH   16
#define WW   16
#define BB   32
#define VV   8192
#define NELEM (BB*CC*HH*WW)   // 1,048,576

typedef short short8 __attribute__((ext_vector_type(8)));
typedef float floatx4 __attribute__((ext_vector_type(4)));

#define CSTR 136   // conv LDS row stride in bf16 elems (128 + 8 pad)

// address-space helpers for global_load_lds
typedef __attribute__((address_space(1))) void as1_void;
typedef __attribute__((address_space(3))) void as3_void;

__device__ __forceinline__ void gl_lds16(const void* g, void* l) {
    // LDS dest is wave-uniform base; HW adds lane*16. Global src is per-lane.
    __builtin_amdgcn_global_load_lds((as1_void*)g, (as3_void*)l, 16, 0, 0);
}

// ---------------- hi/lo bf16 split pack (RNE both) ----------------
__device__ __forceinline__ uint32_t pack_hilo(float x) {
    uint32_t u = __float_as_uint(x);
    uint32_t hb = (u + 0x7fffu + ((u >> 16) & 1u)) & 0xffff0000u;
    float hf = __uint_as_float(hb);
    float lo = x - hf;
    uint32_t ul = __float_as_uint(lo);
    uint32_t lb = ((ul + 0x7fffu + ((ul >> 16) & 1u)) >> 16) & 0xffffu;
    return hb | lb;
}

// ---------------- e_sq + codebook hi/lo plane split + lacc zero ----------------
// 131072 threads: 16 per codebook row.
// ephi/eplo are written in MFMA-fragment order per 128-row vtile:
//   elem (v, c): vt=v>>7, vr=v&127, vh=vr>>6, tj=(vr>>4)&3, l15=vr&15,
//                kc=c>>5, quad=(c>>3)&3, e=c&7
//   off = vt*16384 + ((kc*8 + vh*4 + tj)*64 + quad*16 + l15)*8 + e
// A 64-v half-tile (vt, half) is the 16 chunks {kc*8 + half*4 + g16}, each 1KB.
__global__ void esq_pack(const float* __restrict__ emb, float* __restrict__ esq,
                         short* __restrict__ ephi, short* __restrict__ eplo,
                         float* __restrict__ lacc) {
    int t = blockIdx.x * 256 + threadIdx.x;
    int v = t >> 4, g = t & 15;
    const float* row = emb + (size_t)v * CC + g * 8;
    float4 a = *(const float4*)row;
    float4 b = *(const float4*)(row + 4);
    float s = a.x*a.x + a.y*a.y + a.z*a.z + a.w*a.w
            + b.x*b.x + b.y*b.y + b.z*b.z + b.w*b.w;
    s += __shfl_xor(s, 1, 64);
    s += __shfl_xor(s, 2, 64);
    s += __shfl_xor(s, 4, 64);
    s += __shfl_xor(s, 8, 64);
    if (g == 0) esq[v] = s;
    float vals[8] = {a.x, a.y, a.z, a.w, b.x, b.y, b.z, b.w};
    short hs[8], ls[8];
#pragma unroll
    for (int j = 0; j < 8; j++) {
        uint32_t u = pack_hilo(vals[j]);
        hs[j] = (short)(u >> 16);
        ls[j] = (short)(u & 0xffffu);
    }
    int vt = v >> 7, vr = v & 127;
    int vh = vr >> 6, tj = (vr >> 4) & 3, r15 = vr & 15;
    int kc = g >> 2, quad = g & 3;
    size_t off = (size_t)vt * 16384 + (size_t)((kc * 8 + vh * 4 + tj) * 64 + quad * 16 + r15) * 8;
    *(short8*)(ephi + off) = *(short8*)hs;
    *(short8*)(eplo + off) = *(short8*)ls;
    if (t == 0) lacc[0] = 0.f;
}

// ---------------- pre-transpose + split conv weights: Wt[kphi][kk][cout][cin] ----------------
__global__ void prepack_w(const float* __restrict__ pw, short* __restrict__ Whi,
                          short* __restrict__ Wlo) {
    int id = blockIdx.x * 256 + threadIdx.x;      // 65536 = 4*128*128
    int ci = id & 127, cout = (id >> 7) & 127, kp = id >> 14;
    const float* src = pw + ((size_t)(kp * CC + cout) * CC + ci) * 9;
#pragma unroll
    for (int kk = 0; kk < 9; kk++) {
        uint32_t u = pack_hilo(src[kk]);
        size_t o = ((size_t)(kp * 9 + kk) * CC + cout) * CC + ci;
        Whi[o] = (short)(u >> 16);
        Wlo[o] = (short)(u & 0xffffu);
    }
}

// ---------------- pooled residual (f - f_hat) -> hi/lo planes ----------------
template <bool FIRSTP>
__global__ void pool_pack(const float* __restrict__ f, const float* __restrict__ fh,
                          short* __restrict__ rh, short* __restrict__ rl, int pn) {
    int id = blockIdx.x * 256 + threadIdx.x;
    int c = id % CC;
    int n = id / CC;
    int px = n % pn;
    int py = (n / pn) % pn;
    int b  = n / (pn * pn);
    int s  = HH / pn;
    size_t o = (((size_t)b * CC + c) * HH + py * s) * WW + px * s;
    float acc = 0.f;
    for (int dy = 0; dy < s; dy++)
        for (int dx = 0; dx < s; dx++)
            acc += FIRSTP ? f[o + dy * WW + dx] : (f[o + dy * WW + dx] - fh[o + dy * WW + dx]);
    uint32_t u = pack_hilo(acc * (1.f / (float)(s * s)));
    rh[id] = (short)(u >> 16);
    rl[id] = (short)(u & 0xffffu);
}

// ---------------- MFMA distance v15: v14 + T5 setprio around MFMA clusters ----------------
// block 512 = 8 waves: qq = wave&3 (32-q quarter), vh = wave>>2 (32-v half of the 64-v step).
// 2 independent blocks/CU (proven R7) provide the wave role-diversity that makes
// s_setprio meaningful (guide T5: null on lockstep, pays with phase-split).
// Numerics bit-identical to v12/v14.
__global__ __launch_bounds__(512, 4)
void dist_mfma(const short* __restrict__ rphi, const short* __restrict__ rplo,
               const short* __restrict__ ephi, const short* __restrict__ eplo,
               const float* __restrict__ esq,
               float* __restrict__ pbD, int* __restrict__ pbI,
               int N, int vtPB) {
    __shared__ short Bs[2][2][8192];       // [dbuf][hi/lo][64-v step, chunks kc*4+g16]
    __shared__ float EsqL[1024];           // esq slice (<= 8 vtiles * 128)

    const int tid  = threadIdx.x;
    const int wave = tid >> 6, ln = tid & 63;
    const int quad = ln >> 4, l15 = ln & 15;
    const int qq = wave & 3, vh = wave >> 2;
    const int qb0 = blockIdx.x * 128;
    const int vslices = gridDim.y;
    const int vt0 = blockIdx.y * vtPB;     // in 128-v vtile units
    const int nsteps = vtPB * 2;           // 64-v steps

// stage 64-v half-tile (vt0+(s>>1), s&1): 16 chunks of 1KB per plane, 2/plane/wave
#define STAGE_STEP(buf_, s_) do {                                                    \
        const int vt_ = vt0 + ((s_) >> 1);                                           \
        const int hf_ = (s_) & 1;                                                    \
        _Pragma("unroll")                                                            \
        for (int i_ = 0; i_ < 2; i_++) {                                             \
            const int ck_ = wave * 2 + i_;                                           \
            const int kc_ = ck_ >> 2, g_ = ck_ & 3;                                  \
            const size_t so_ = (size_t)vt_ * 32768 +                                 \
                               (size_t)(kc_ * 8 + hf_ * 4 + g_) * 1024;              \
            gl_lds16((const char*)ephi + so_ + ln * 16, (char*)&Bs[(buf_)][0][0] + ck_ * 1024); \
            gl_lds16((const char*)eplo + so_ + ln * 16, (char*)&Bs[(buf_)][1][0] + ck_ * 1024); \
        } } while (0)

    // prologue: stage step 0, the esq slice, and A frags; full drain + barrier once
    STAGE_STEP(0, 0);
    {
        int echunks = (vtPB * 512 + 1023) >> 10;   // 1KB chunks of the esq slice (bytes)
        if (wave < echunks)
            gl_lds16((const char*)(esq + vt0 * 128) + wave * 1024 + ln * 16,
                     (char*)EsqL + wave * 1024);
    }

    // A fragments loaded once: 32 q per wave (rows may exceed N: garbage but finite;
    // outputs guarded). 16 short8 = 64 VGPRs.
    short8 av[2][4], aw[2][4];
#pragma unroll
    for (int ti = 0; ti < 2; ti++) {
        const size_t arow = (size_t)(qb0 + qq * 32 + ti * 16 + l15) * CC + quad * 8;
#pragma unroll
        for (int kc = 0; kc < 4; kc++) {
            av[ti][kc] = *(const short8*)(rphi + arow + kc * 32);
            aw[ti][kc] = *(const short8*)(rplo + arow + kc * 32);
        }
    }
    __builtin_amdgcn_sched_barrier(0);
    asm volatile("s_waitcnt vmcnt(0)" ::: "memory");   // stage0 + esq + A resident
    __builtin_amdgcn_sched_barrier(0);
    __builtin_amdgcn_s_barrier();
    __builtin_amdgcn_sched_barrier(0);

    float bD[2][4];
    int   bI[2][4];
#pragma unroll
    for (int ti = 0; ti < 2; ti++)
#pragma unroll
        for (int r = 0; r < 4; r++) { bD[ti][r] = INFINITY; bI[ti][r] = 0; }

    int cur = 0;
    for (int s = 0; s < nsteps; s++) {
        // issue next-step stage first; it lands during this step's compute
        if (s + 1 < nsteps) STAGE_STEP(cur ^ 1, s + 1);
        __builtin_amdgcn_sched_barrier(0);   // pin stage issue before compute

        floatx4 acc[2][2];
        floatx4 z = {0.f, 0.f, 0.f, 0.f};
#pragma unroll
        for (int ti = 0; ti < 2; ti++)
#pragma unroll
            for (int tj = 0; tj < 2; tj++) acc[ti][tj] = z;

        // fragment reads: chunk (kc*4 + vh*2 + tj)*1024B + lane*16B -> conflict-free linear
        const short* Bh = &Bs[cur][0][0];
        const short* Bl = &Bs[cur][1][0];
#pragma unroll
        for (int kc = 0; kc < 4; kc++) {
            short8 bh[2], bl[2];
#pragma unroll
            for (int tj = 0; tj < 2; tj++) {
                const int ck = kc * 4 + vh * 2 + tj;
                bh[tj] = *(const short8*)(Bh + ck * 512 + ln * 8);
                bl[tj] = *(const short8*)(Bl + ck * 512 + ln * 8);
            }
            // pass-major within kc: 4 runs of 4 independent MFMAs.
            // Per-acc order per kc: av*bh, aw*bh, av*bl, aw*bl -> bit-identical.
            __builtin_amdgcn_s_setprio(1);
#pragma unroll
            for (int tj = 0; tj < 2; tj++)
#pragma unroll
                for (int ti = 0; ti < 2; ti++)
                    acc[ti][tj] = __builtin_amdgcn_mfma_f32_16x16x32_bf16(av[ti][kc], bh[tj], acc[ti][tj], 0, 0, 0);
#pragma unroll
            for (int tj = 0; tj < 2; tj++)
#pragma unroll
                for (int ti = 0; ti < 2; ti++)
                    acc[ti][tj] = __builtin_amdgcn_mfma_f32_16x16x32_bf16(aw[ti][kc], bh[tj], acc[ti][tj], 0, 0, 0);
#pragma unroll
            for (int tj = 0; tj < 2; tj++)
#pragma unroll
                for (int ti = 0; ti < 2; ti++)
                    acc[ti][tj] = __builtin_amdgcn_mfma_f32_16x16x32_bf16(av[ti][kc], bl[tj], acc[ti][tj], 0, 0, 0);
#pragma unroll
            for (int tj = 0; tj < 2; tj++)
#pragma unroll
                for (int ti = 0; ti < 2; ti++)
                    acc[ti][tj] = __builtin_amdgcn_mfma_f32_16x16x32_bf16(aw[ti][kc], bl[tj], acc[ti][tj], 0, 0, 0);
            __builtin_amdgcn_s_setprio(0);
        }

        // dist = esq - 2*dot; esq from LDS (lgkmcnt only).
        // v ascending over s/tj per lane -> strict < keeps first min
        const int v0 = (vt0 + (s >> 1)) * 128 + (s & 1) * 64;
#pragma unroll
        for (int tj = 0; tj < 2; tj++) {
            int vg = v0 + vh * 32 + tj * 16 + l15;
            float ev = EsqL[s * 64 + vh * 32 + tj * 16 + l15];
#pragma unroll
            for (int ti = 0; ti < 2; ti++)
#pragma unroll
                for (int r = 0; r < 4; r++) {
                    float d = fmaf(-2.f, acc[ti][tj][r], ev);
                    if (d < bD[ti][r]) { bD[ti][r] = d; bI[ti][r] = vg; }
                }
        }

        // single barrier per step: drain the in-flight stage (landed under compute),
        // then sync. After this barrier all waves are done reading buf[cur].
        __builtin_amdgcn_sched_barrier(0);
        asm volatile("s_waitcnt vmcnt(0)" ::: "memory");
        __builtin_amdgcn_sched_barrier(0);
        __builtin_amdgcn_s_barrier();
        __builtin_amdgcn_sched_barrier(0);
        cur ^= 1;
    }
#undef STAGE_STEP

    // cross-lane reduce within 16-lane groups (same q, different v), tie -> lower v
#pragma unroll
    for (int ti = 0; ti < 2; ti++)
#pragma unroll
        for (int r = 0; r < 4; r++) {
            float d = bD[ti][r];
            int   v = bI[ti][r];
#pragma unroll
            for (int m = 1; m <= 8; m <<= 1) {
                float od = __shfl_xor(d, m, 64);
                int   ov = __shfl_xor(v, m, 64);
                if (od < d || (od == d && ov < v)) { d = od; v = ov; }
            }
            if (l15 == 0) {
                int q = qb0 + qq * 32 + ti * 16 + quad * 4 + r;
                if (q < N) {
                    size_t o = (size_t)q * (vslices * 2) + blockIdx.y * 2 + vh;
                    pbD[o] = d;
                    pbI[o] = v;
                }
            }
        }
}

// ---------------- Keys cubic a=-0.5 (matches jax) ----------------
__device__ __forceinline__ float cubic_k(float x) {
    if (x <= 1.f) return (1.5f * x - 2.5f) * x * x + 1.f;
    if (x < 2.f)  return ((-0.5f * x + 2.5f) * x - 4.f) * x + 2.f;
    return 0.f;
}

// ---------------- fused argmin + upsample -> h planes ----------------
// grid = (32 b * 16 cig), 256 threads = pixel; 8 channels per thread.
// Partial-min merge over vsplit slices is parallel (all 256 threads + tree).
template <int PN>
__global__ __launch_bounds__(256)
void upsample_pack(const float* __restrict__ emb,
                   const float* __restrict__ pbD, const int* __restrict__ pbI, int vsplit,
                   short* __restrict__ hhi, short* __restrict__ hlo,
                   float* __restrict__ hfp) {
    const int t = threadIdx.x;
    const int x = t & 15, y = t >> 4;
    const int b = blockIdx.x >> 4;
    const int c0 = (blockIdx.x & 15) * 8;

    float val[8];

    if constexpr (PN == 16) {
        int q = b * 256 + t;
        float bd = pbD[(size_t)q * vsplit];
        int   bi = pbI[(size_t)q * vsplit];
        for (int j = 1; j < vsplit; j++) {
            float d  = pbD[(size_t)q * vsplit + j];
            int   i2 = pbI[(size_t)q * vsplit + j];
            if (d < bd || (d == bd && i2 < bi)) { bd = d; bi = i2; }
        }
        float4 v0 = *(const float4*)(emb + (size_t)bi * CC + c0);
        float4 v1 = *(const float4*)(emb + (size_t)bi * CC + c0 + 4);
        val[0]=v0.x; val[1]=v0.y; val[2]=v0.z; val[3]=v0.w;
        val[4]=v1.x; val[5]=v1.y; val[6]=v1.z; val[7]=v1.w;
    } else {
        constexpr int NQ = PN * PN;      // 1,4,16,64
        constexpr int KK = 256 / NQ;
        __shared__ int idxL[NQ];
        __shared__ float S[NQ][8];
        __shared__ float prd[256];
        __shared__ int   pri[256];

        // strided partial min: thread t covers query (t & NQ-1), slices t/NQ :: KK
        {
            const int qi = t & (NQ - 1);
            const int kk = t / NQ;
            float bd = INFINITY; int bi = 0;
            for (int j = kk; j < vsplit; j += KK) {
                float d  = pbD[(size_t)(b * NQ + qi) * vsplit + j];
                int   i2 = pbI[(size_t)(b * NQ + qi) * vsplit + j];
                if (d < bd || (d == bd && i2 < bi)) { bd = d; bi = i2; }
            }
            prd[t] = bd; pri[t] = bi;
        }
        __syncthreads();
        if (t < 64) {
            float d = prd[t]; int v = pri[t];
            for (int p = t + 64; p < 256; p += 64) {
                float d2 = prd[p]; int v2 = pri[p];
                if (d2 < d || (d2 == d && v2 < v)) { d = d2; v = v2; }
            }
#pragma unroll
            for (int m = NQ; m < 64; m <<= 1) {
                float d2 = __shfl_xor(d, m, 64);
                int   v2 = __shfl_xor(v, m, 64);
                if (d2 < d || (d2 == d && v2 < v)) { d = d2; v = v2; }
            }
            if (t < NQ) idxL[t] = v;
        }
        __syncthreads();
        if (t < NQ) {
            float4 v0 = *(const float4*)(emb + (size_t)idxL[t] * CC + c0);
            float4 v1 = *(const float4*)(emb + (size_t)idxL[t] * CC + c0 + 4);
            S[t][0]=v0.x; S[t][1]=v0.y; S[t][2]=v0.z; S[t][3]=v0.w;
            S[t][4]=v1.x; S[t][5]=v1.y; S[t][6]=v1.z; S[t][7]=v1.w;
        }
        __syncthreads();

        const float sc = (float)PN / 16.f;
        float sy = (y + 0.5f) * sc - 0.5f;
        float sx = (x + 0.5f) * sc - 0.5f;
        int iy0 = (int)floorf(sy) - 1;
        int ix0 = (int)floorf(sx) - 1;
        float wy[4], wx[4];
        float ssy = 0.f, ssx = 0.f;
#pragma unroll
        for (int k = 0; k < 4; k++) {
            int iy = iy0 + k, ix = ix0 + k;
            float a = (iy >= 0 && iy < PN) ? cubic_k(fabsf(sy - (float)iy)) : 0.f;
            float bb = (ix >= 0 && ix < PN) ? cubic_k(fabsf(sx - (float)ix)) : 0.f;
            wy[k] = a; ssy += a;
            wx[k] = bb; ssx += bb;
        }
        float ry = 1.f / ssy, rx = 1.f / ssx;
#pragma unroll
        for (int k = 0; k < 4; k++) { wy[k] *= ry; wx[k] *= rx; }

#pragma unroll
        for (int j = 0; j < 8; j++) val[j] = 0.f;
#pragma unroll
        for (int k4 = 0; k4 < 4; k4++) {
            int iy = iy0 + k4;
            if (iy < 0 || iy >= PN) continue;
#pragma unroll
            for (int j4 = 0; j4 < 4; j4++) {
                int ix = ix0 + j4;
                if (ix < 0 || ix >= PN) continue;
                float w = wy[k4] * wx[j4];
                const float* sp = S[iy * PN + ix];
#pragma unroll
                for (int j = 0; j < 8; j++) val[j] = fmaf(w, sp[j], val[j]);
            }
        }
    }

    short hs[8], ls[8];
#pragma unroll
    for (int j = 0; j < 8; j++) {
        uint32_t u = pack_hilo(val[j]);
        hs[j] = (short)(u >> 16);
        ls[j] = (short)(u & 0xffffu);
    }
    size_t ho = ((size_t)(b * 18 + y + 1) * 18 + (x + 1)) * CC + c0;
    *(short8*)(hhi + ho) = *(short8*)hs;
    *(short8*)(hlo + ho) = *(short8*)ls;
#pragma unroll
    for (int j = 0; j < 8; j++)
        hfp[((size_t)b * CC + c0 + j) * 256 + t] = val[j];
}

// ---------------- MFMA conv3x3: LDS weights, T14 async-split staging ----------------
// Weights for kk are preloaded to REGISTERS during kk-1's MFMA phase (HBM/L2 latency
// hides under compute); the ds_write happens inside the barrier pair. Same data,
// same compute order as before -> bit-identical.
template <bool FIRST>
__global__ __launch_bounds__(256)
void conv_mfma(const short* __restrict__ Whi, const short* __restrict__ Wlo,
               const short* __restrict__ hhi, const short* __restrict__ hlo,
               const float* __restrict__ hfp, const float* __restrict__ pb,
               const float* __restrict__ f, float* __restrict__ f_hat,
               float* __restrict__ lacc, int kphi) {
    __shared__ short Bsh[64 * CSTR];
    __shared__ short Bsl[64 * CSTR];
    __shared__ float red[2][16][65];
    __shared__ float lred[2];

    const int t = threadIdx.x;
    const int wave = t >> 6, lane = t & 63;
    const int quad = lane >> 4, l15 = lane & 15;
    const int pxg = wave & 1, kh = wave >> 1;
    const int cH = blockIdx.x & 1;
    const int pc = blockIdx.x >> 1;
    const int b = pc >> 3;
    const int pxbase = (pc & 7) * 32;
    const int pa = pxbase + pxg * 16 + l15;
    const int ya = pa >> 4, xa = pa & 15;

    floatx4 acc[4];
    floatx4 z = {0.f, 0.f, 0.f, 0.f};
#pragma unroll
    for (int nt = 0; nt < 4; nt++) acc[nt] = z;

    // per-thread staging slice: 4 chunks x 2 planes = 8 short8 in regs
    const int srow = t >> 4, scol = (t & 15) * 8;   // chunk i covers row srow + i*16
    short8 rh[4], rl[4];
    {
        const short* gh = Whi + ((size_t)(kphi * 9 + 0) * CC + cH * 64) * CC;
        const short* gl = Wlo + ((size_t)(kphi * 9 + 0) * CC + cH * 64) * CC;
#pragma unroll
        for (int i = 0; i < 4; i++) {
            rh[i] = *(const short8*)(gh + (srow + i * 16) * CC + scol);
            rl[i] = *(const short8*)(gl + (srow + i * 16) * CC + scol);
        }
    }

    for (int kk = 0; kk < 9; kk++) {
        __syncthreads();          // all waves done reading previous kk's weights
#pragma unroll
        for (int i = 0; i < 4; i++) {
            *(short8*)&Bsh[(srow + i * 16) * CSTR + scol] = rh[i];
            *(short8*)&Bsl[(srow + i * 16) * CSTR + scol] = rl[i];
        }
        __syncthreads();          // writes visible

        // preload kk+1 weights to regs; latency hides under this kk's MFMAs
        if (kk < 8) {
            const short* gh = Whi + ((size_t)(kphi * 9 + kk + 1) * CC + cH * 64) * CC;
            const short* gl = Wlo + ((size_t)(kphi * 9 + kk + 1) * CC + cH * 64) * CC;
#pragma unroll
            for (int i = 0; i < 4; i++) {
                rh[i] = *(const short8*)(gh + (srow + i * 16) * CC + scol);
                rl[i] = *(const short8*)(gl + (srow + i * 16) * CC + scol);
            }
        }

        const int ky = kk / 3, kx = kk % 3;
        const size_t aoff = ((size_t)(b * 18 + ya + ky) * 18 + (xa + kx)) * CC + quad * 8;
#pragma unroll
        for (int i2 = 0; i2 < 2; i2++) {
            const int cic = kh * 2 + i2;
            short8 ah = *(const short8*)(hhi + aoff + cic * 32);
            short8 al = *(const short8*)(hlo + aoff + cic * 32);
#pragma unroll
            for (int nt = 0; nt < 4; nt++) {
                short8 bh = *(const short8*)&Bsh[(nt * 16 + l15) * CSTR + cic * 32 + quad * 8];
                short8 bl = *(const short8*)&Bsl[(nt * 16 + l15) * CSTR + cic * 32 + quad * 8];
                acc[nt] = __builtin_amdgcn_mfma_f32_16x16x32_bf16(ah, bh, acc[nt], 0, 0, 0);
                acc[nt] = __builtin_amdgcn_mfma_f32_16x16x32_bf16(al, bh, acc[nt], 0, 0, 0);
                acc[nt] = __builtin_amdgcn_mfma_f32_16x16x32_bf16(ah, bl, acc[nt], 0, 0, 0);
            }
        }
    }

    __syncthreads();
    if (kh == 1) {
#pragma unroll
        for (int nt = 0; nt < 4; nt++)
#pragma unroll
            for (int r = 0; r < 4; r++)
                red[pxg][quad * 4 + r][nt * 16 + l15] = acc[nt][r];
    }
    __syncthreads();

    if (kh == 0) {
        const int pe = pxbase + pxg * 16 + quad * 4;
        float lsum = 0.f;
#pragma unroll
        for (int nt = 0; nt < 4; nt++) {
            int cout = cH * 64 + nt * 16 + l15;
            float bias = pb[kphi * CC + cout];
            size_t gi = ((size_t)b * CC + cout) * 256 + pe;
            float4 h4  = *(const float4*)(hfp + gi);
            float4 f4  = *(const float4*)(f + gi);
            float4 fh4 = FIRST ? make_float4(0.f, 0.f, 0.f, 0.f) : *(const float4*)(f_hat + gi);
            float c0 = acc[nt][0] + red[pxg][quad * 4 + 0][nt * 16 + l15] + bias;
            float c1 = acc[nt][1] + red[pxg][quad * 4 + 1][nt * 16 + l15] + bias;
            float c2 = acc[nt][2] + red[pxg][quad * 4 + 2][nt * 16 + l15] + bias;
            float c3 = acc[nt][3] + red[pxg][quad * 4 + 3][nt * 16 + l15] + bias;
            float o0 = fh4.x + 0.5f * h4.x + 0.5f * c0;
            float o1 = fh4.y + 0.5f * h4.y + 0.5f * c1;
            float o2 = fh4.z + 0.5f * h4.z + 0.5f * c2;
            float o3 = fh4.w + 0.5f * h4.w + 0.5f * c3;
            *(float4*)(f_hat + gi) = make_float4(o0, o1, o2, o3);
            float d0 = o0 - f4.x, d1 = o1 - f4.y, d2 = o2 - f4.z, d3 = o3 - f4.w;
            lsum += d0*d0 + d1*d1 + d2*d2 + d3*d3;
        }
#pragma unroll
        for (int off = 32; off; off >>= 1) lsum += __shfl_down(lsum, off, 64);
        if (lane == 0) lred[pxg] = lsum;
    }
    __syncthreads();
    if (t == 0) atomicAdd(lacc, lred[0] + lred[1]);
}

__global__ void finalize_kernel(const float* __restrict__ lacc, float* __restrict__ out_loss) {
    *out_loss = lacc[0] * (0.25f / (float)NELEM);   // (1+BETA)/SN * sum of means
}

extern "C" void kernel_launch(void* const* d_in, const int* in_sizes, int n_in,
                              void* d_out, int out_size, void* d_ws, size_t ws_size,
                              hipStream_t stream) {
    const float* f   = (const float*)d_in[0];
    const float* emb = (const float*)d_in[1];
    const float* pw  = (const float*)d_in[2];
    const float* pb  = (const float*)d_in[3];
    float* out = (float*)d_out;

    uint32_t* w32 = (uint32_t*)d_ws;
    short* rphi = (short*)(w32);                    // 1,048,576 shorts
    short* rplo = (short*)(w32 + 524288);
    short* ephi = (short*)(w32 + 1048576);          // 1,048,576 shorts
    short* eplo = (short*)(w32 + 1572864);
    short* Whi  = (short*)(w32 + 2097152);          // 589,824 shorts
    short* Wlo  = (short*)(w32 + 2392064);
    short* hhi  = (short*)(w32 + 2686976);          // 1,327,104 shorts
    short* hlo  = (short*)(w32 + 3350528);
    float* hfp  = (float*)(w32 + 4014080);          // 1,048,576 f
    float* esq  = (float*)(w32 + 5062656);          // 8192
    float* pbD  = (float*)(w32 + 5070848);          // 262144
    int*   pbI  = (int*)  (w32 + 5332992);          // 262144
    float* lacc = (float*)(w32 + 5595136);          // 1

    // zero halos of h planes (hhi & hlo contiguous)
    hipMemsetAsync(hhi, 0, (size_t)2 * 1327104 * sizeof(short), stream);

    esq_pack<<<512, 256, 0, stream>>>(emb, esq, ephi, eplo, lacc);
    prepack_w<<<256, 256, 0, stream>>>(pw, Whi, Wlo);

    // mirror np.linspace(1/12, 11/12, 4) exactly in float64
    double start = 1.0 / 12.0;
    double stop  = 1.0 - 1.0 / 12.0;
    double step  = (stop - start) / 3.0;
    double ticks[4] = {start, 1.0 * step + start, 2.0 * step + start, stop};

    const int pns[5]    = {1, 2, 4, 8, 16};
    const int qb5[5]    = {1, 1, 4, 16, 64};        // ceil(N/128)
    const int vs5[5]    = {64, 64, 64, 32, 8};      // vslices (x vtPB x 128 = 8192)
    const int vtPB5[5]  = {1, 1, 1, 2, 8};          // 128-v vtiles per block

    for (int si = 0; si < 5; si++) {
        int pn = pns[si];
        int N  = BB * pn * pn;
        double tt = (double)si / 4.0;
        int kphi = 0;
        double bd = fabs(ticks[0] - tt);
        for (int i = 1; i < 4; i++) {
            double d = fabs(ticks[i] - tt);
            if (d < bd) { bd = d; kphi = i; }   // np.argmin: first occurrence
        }

        if (si == 0) pool_pack<true><<<(N * CC) / 256, 256, 0, stream>>>(f, out, rphi, rplo, pn);
        else         pool_pack<false><<<(N * CC) / 256, 256, 0, stream>>>(f, out, rphi, rplo, pn);

        dim3 dgrid(qb5[si], vs5[si]);
        dist_mfma<<<dgrid, 512, 0, stream>>>(rphi, rplo, ephi, eplo, esq, pbD, pbI, N, vtPB5[si]);

        int vsplit = vs5[si] * 2;
        switch (pn) {
            case 1:  upsample_pack<1><<<512, 256, 0, stream>>>(emb, pbD, pbI, vsplit, hhi, hlo, hfp); break;
            case 2:  upsample_pack<2><<<512, 256, 0, stream>>>(emb, pbD, pbI, vsplit, hhi, hlo, hfp); break;
            case 4:  upsample_pack<4><<<512, 256, 0, stream>>>(emb, pbD, pbI, vsplit, hhi, hlo, hfp); break;
            case 8:  upsample_pack<8><<<512, 256, 0, stream>>>(emb, pbD, pbI, vsplit, hhi, hlo, hfp); break;
            default: upsample_pack<16><<<512, 256, 0, stream>>>(emb, pbD, pbI, vsplit, hhi, hlo, hfp); break;
        }

        if (si == 0) conv_mfma<true><<<512, 256, 0, stream>>>(Whi, Wlo, hhi, hlo, hfp, pb, f, out, lacc, kphi);
        else         conv_mfma<false><<<512, 256, 0, stream>>>(Whi, Wlo, hhi, hlo, hfp, pb, f, out, lacc, kphi);
    }

    finalize_kernel<<<1, 1, 0, stream>>>(lacc, out + NELEM);
}

// Round 12
// 392.711 us; speedup vs baseline: 1.1081x; 1.1034x over previous
//
#include <hip/hip_runtime.h>
#include <math.h>

#define CC   128
#define HH   16
#define WW   16
#define BB   32
#define VV   8192
#define NELEM (BB*CC*HH*WW)   // 1,048,576

typedef short short8 __attribute__((ext_vector_type(8)));
typedef float floatx4 __attribute__((ext_vector_type(4)));

#define CSTR 136   // conv LDS row stride in bf16 elems (128 + 8 pad)

// address-space helpers for global_load_lds
typedef __attribute__((address_space(1))) void as1_void;
typedef __attribute__((address_space(3))) void as3_void;

__device__ __forceinline__ void gl_lds16(const void* g, void* l) {
    // LDS dest is wave-uniform base; HW adds lane*16. Global src is per-lane.
    __builtin_amdgcn_global_load_lds((as1_void*)g, (as3_void*)l, 16, 0, 0);
}

// ---------------- hi/lo bf16 split pack (RNE both) ----------------
__device__ __forceinline__ uint32_t pack_hilo(float x) {
    uint32_t u = __float_as_uint(x);
    uint32_t hb = (u + 0x7fffu + ((u >> 16) & 1u)) & 0xffff0000u;
    float hf = __uint_as_float(hb);
    float lo = x - hf;
    uint32_t ul = __float_as_uint(lo);
    uint32_t lb = ((ul + 0x7fffu + ((ul >> 16) & 1u)) >> 16) & 0xffffu;
    return hb | lb;
}

// ---------------- e_sq + codebook hi/lo plane split + lacc zero ----------------
// 131072 threads: 16 per codebook row.
// ephi/eplo are written in MFMA-fragment order per 128-row vtile:
//   elem (v, c): vt=v>>7, vr=v&127, vh=vr>>6, tj=(vr>>4)&3, l15=vr&15,
//                kc=c>>5, quad=(c>>3)&3, e=c&7
//   off = vt*16384 + ((kc*8 + vh*4 + tj)*64 + quad*16 + l15)*8 + e
// A 64-v half-tile (vt, half) is the 16 chunks {kc*8 + half*4 + g16}, each 1KB.
__global__ void esq_pack(const float* __restrict__ emb, float* __restrict__ esq,
                         short* __restrict__ ephi, short* __restrict__ eplo,
                         float* __restrict__ lacc) {
    int t = blockIdx.x * 256 + threadIdx.x;
    int v = t >> 4, g = t & 15;
    const float* row = emb + (size_t)v * CC + g * 8;
    float4 a = *(const float4*)row;
    float4 b = *(const float4*)(row + 4);
    float s = a.x*a.x + a.y*a.y + a.z*a.z + a.w*a.w
            + b.x*b.x + b.y*b.y + b.z*b.z + b.w*b.w;
    s += __shfl_xor(s, 1, 64);
    s += __shfl_xor(s, 2, 64);
    s += __shfl_xor(s, 4, 64);
    s += __shfl_xor(s, 8, 64);
    if (g == 0) esq[v] = s;
    float vals[8] = {a.x, a.y, a.z, a.w, b.x, b.y, b.z, b.w};
    short hs[8], ls[8];
#pragma unroll
    for (int j = 0; j < 8; j++) {
        uint32_t u = pack_hilo(vals[j]);
        hs[j] = (short)(u >> 16);
        ls[j] = (short)(u & 0xffffu);
    }
    int vt = v >> 7, vr = v & 127;
    int vh = vr >> 6, tj = (vr >> 4) & 3, r15 = vr & 15;
    int kc = g >> 2, quad = g & 3;
    size_t off = (size_t)vt * 16384 + (size_t)((kc * 8 + vh * 4 + tj) * 64 + quad * 16 + r15) * 8;
    *(short8*)(ephi + off) = *(short8*)hs;
    *(short8*)(eplo + off) = *(short8*)ls;
    if (t == 0) lacc[0] = 0.f;
}

// ---------------- pre-transpose + split conv weights: Wt[kphi][kk][cout][cin] ----------------
__global__ void prepack_w(const float* __restrict__ pw, short* __restrict__ Whi,
                          short* __restrict__ Wlo) {
    int id = blockIdx.x * 256 + threadIdx.x;      // 65536 = 4*128*128
    int ci = id & 127, cout = (id >> 7) & 127, kp = id >> 14;
    const float* src = pw + ((size_t)(kp * CC + cout) * CC + ci) * 9;
#pragma unroll
    for (int kk = 0; kk < 9; kk++) {
        uint32_t u = pack_hilo(src[kk]);
        size_t o = ((size_t)(kp * 9 + kk) * CC + cout) * CC + ci;
        Whi[o] = (short)(u >> 16);
        Wlo[o] = (short)(u & 0xffffu);
    }
}

// ---------------- pooled residual (f - f_hat) -> hi/lo planes, PARALLEL ----------------
// Every thread reads exactly 4 f elements; outputs reduced by a T-lane shuffle tree.
// PN=1: T=64 (full 16x16 window/wave), PN=2: T=16, PN=4: T=4 (one float4/thread),
// PN=8: T=1 (sequential 2x2, BIT-IDENTICAL to original), PN=16: original 1-elem path.
template <int PN, bool FIRSTP>
__global__ __launch_bounds__(256)
void pool_pack(const float* __restrict__ f, const float* __restrict__ fh,
               short* __restrict__ rh, short* __restrict__ rl) {
    const int tid = threadIdx.x;
    const int gid = blockIdx.x * 256 + tid;

    if constexpr (PN == 16) {
        int c = gid % CC;
        int n = gid / CC;
        int px = n % 16, py = (n / 16) % 16, b = n / 256;
        size_t o = (((size_t)b * CC + c) * HH + py) * WW + px;
        float acc = FIRSTP ? f[o] : (f[o] - fh[o]);
        uint32_t u = pack_hilo(acc);
        rh[gid] = (short)(u >> 16);
        rl[gid] = (short)(u & 0xffffu);
        return;
    } else if constexpr (PN == 8) {
        // 2x2 window, sequential order identical to original
        int c = gid & 127;
        int n = gid >> 7;
        int px = n & 7, py = (n >> 3) & 7, b = n >> 6;
        size_t o = (((size_t)b * CC + c) * HH + py * 2) * WW + px * 2;
        float acc = 0.f;
        acc += FIRSTP ? f[o]      : (f[o]      - fh[o]);
        acc += FIRSTP ? f[o + 1]  : (f[o + 1]  - fh[o + 1]);
        acc += FIRSTP ? f[o + 16] : (f[o + 16] - fh[o + 16]);
        acc += FIRSTP ? f[o + 17] : (f[o + 17] - fh[o + 17]);
        uint32_t u = pack_hilo(acc * 0.25f);
        rh[gid] = (short)(u >> 16);
        rl[gid] = (short)(u & 0xffffu);
        return;
    } else {
        constexpr int T = (PN == 1) ? 64 : (PN == 2) ? 16 : 4;   // lanes per output
        const int out = gid / T;
        const int sub = tid & (T - 1);
        const int c = out & 127;
        const int n = out >> 7;
        const int px = n % PN, py = (n / PN) % PN, b = n / (PN * PN);
        constexpr int S = 16 / PN;                // window side
        // thread covers 4 consecutive x in one row of the window
        const int rowsPerT = (T * 4) / S;         // how many threads per... rows covered:
        // layout: thread sub -> row = sub / (S/4), col4 = (sub % (S/4)) * 4
        const int row = sub / (S / 4);
        const int col4 = (sub % (S / 4)) * 4;
        size_t o = (((size_t)b * CC + c) * HH + py * S + row) * WW + px * S + col4;
        float4 a = *(const float4*)(f + o);
        float sum;
        if (FIRSTP) {
            sum = ((a.x + a.y) + a.z) + a.w;
            // preserve elementwise chain: a.x + a.y + a.z + a.w sequential
            sum = a.x; sum += a.y; sum += a.z; sum += a.w;
        } else {
            float4 h = *(const float4*)(fh + o);
            sum = (a.x - h.x); sum += (a.y - h.y); sum += (a.z - h.z); sum += (a.w - h.w);
        }
#pragma unroll
        for (int m = 1; m < T; m <<= 1) sum += __shfl_xor(sum, m, 64);
        if (sub == 0) {
            uint32_t u = pack_hilo(sum * (1.f / (float)(S * S)));
            rh[out] = (short)(u >> 16);
            rl[out] = (short)(u & 0xffffu);
        }
        (void)rowsPerT;
    }
}

// ---------------- MFMA distance v16: v15 with per-block st64 64-v steps ----------------
// block 512 = 8 waves: qq = wave&3 (32-q quarter), vh = wave>>2 (32-v half of the 64-v step).
// Grid (qb, vs64): block covers q [bx*128,+128) x v [by*st64*64, +st64*64).
// Small scales get 128-512 blocks (vs 64 before) -> latency halved. si4 identical to v15.
// Numerics bit-identical (same per-(q,v) MFMA order, same v-ascending tie-break).
__global__ __launch_bounds__(512, 4)
void dist_mfma(const short* __restrict__ rphi, const short* __restrict__ rplo,
               const short* __restrict__ ephi, const short* __restrict__ eplo,
               const float* __restrict__ esq,
               float* __restrict__ pbD, int* __restrict__ pbI,
               int N, int st64) {
    __shared__ short Bs[2][2][8192];       // [dbuf][hi/lo][64-v step, chunks kc*4+g16]
    __shared__ float EsqL[1024];           // esq slice (<= 16 steps * 64)

    const int tid  = threadIdx.x;
    const int wave = tid >> 6, ln = tid & 63;
    const int quad = ln >> 4, l15 = ln & 15;
    const int qq = wave & 3, vh = wave >> 2;
    const int qb0 = blockIdx.x * 128;
    const int vslices = gridDim.y;
    const int v64b = blockIdx.y * st64;    // base in 64-v units
    const int nsteps = st64;

// stage 64-v half-tile (v64b+s): vt=(v64b+s)>>1, hf=(v64b+s)&1; 16 chunks of 1KB/plane
#define STAGE_STEP(buf_, s_) do {                                                    \
        const int h_  = v64b + (s_);                                                 \
        const int vt_ = h_ >> 1, hf_ = h_ & 1;                                       \
        _Pragma("unroll")                                                            \
        for (int i_ = 0; i_ < 2; i_++) {                                             \
            const int ck_ = wave * 2 + i_;                                           \
            const int kc_ = ck_ >> 2, g_ = ck_ & 3;                                  \
            const size_t so_ = (size_t)vt_ * 32768 +                                 \
                               (size_t)(kc_ * 8 + hf_ * 4 + g_) * 1024;              \
            gl_lds16((const char*)ephi + so_ + ln * 16, (char*)&Bs[(buf_)][0][0] + ck_ * 1024); \
            gl_lds16((const char*)eplo + so_ + ln * 16, (char*)&Bs[(buf_)][1][0] + ck_ * 1024); \
        } } while (0)

    // prologue: stage step 0, the esq slice, and A frags; full drain + barrier once
    STAGE_STEP(0, 0);
    {
        int echunks = (st64 * 256 + 1023) >> 10;   // 1KB chunks of esq slice bytes
        if (wave < echunks)
            gl_lds16((const char*)(esq + v64b * 64) + wave * 1024 + ln * 16,
                     (char*)EsqL + wave * 1024);
    }

    // A fragments loaded once: 32 q per wave (rows may exceed N: garbage but finite;
    // outputs guarded). 16 short8 = 64 VGPRs.
    short8 av[2][4], aw[2][4];
#pragma unroll
    for (int ti = 0; ti < 2; ti++) {
        const size_t arow = (size_t)(qb0 + qq * 32 + ti * 16 + l15) * CC + quad * 8;
#pragma unroll
        for (int kc = 0; kc < 4; kc++) {
            av[ti][kc] = *(const short8*)(rphi + arow + kc * 32);
            aw[ti][kc] = *(const short8*)(rplo + arow + kc * 32);
        }
    }
    __builtin_amdgcn_sched_barrier(0);
    asm volatile("s_waitcnt vmcnt(0)" ::: "memory");   // stage0 + esq + A resident
    __builtin_amdgcn_sched_barrier(0);
    __builtin_amdgcn_s_barrier();
    __builtin_amdgcn_sched_barrier(0);

    float bD[2][4];
    int   bI[2][4];
#pragma unroll
    for (int ti = 0; ti < 2; ti++)
#pragma unroll
        for (int r = 0; r < 4; r++) { bD[ti][r] = INFINITY; bI[ti][r] = 0; }

    int cur = 0;
    for (int s = 0; s < nsteps; s++) {
        // issue next-step stage first; it lands during this step's compute
        if (s + 1 < nsteps) STAGE_STEP(cur ^ 1, s + 1);
        __builtin_amdgcn_sched_barrier(0);   // pin stage issue before compute

        floatx4 acc[2][2];
        floatx4 z = {0.f, 0.f, 0.f, 0.f};
#pragma unroll
        for (int ti = 0; ti < 2; ti++)
#pragma unroll
            for (int tj = 0; tj < 2; tj++) acc[ti][tj] = z;

        // fragment reads: chunk (kc*4 + vh*2 + tj)*1024B + lane*16B -> conflict-free linear
        const short* Bh = &Bs[cur][0][0];
        const short* Bl = &Bs[cur][1][0];
#pragma unroll
        for (int kc = 0; kc < 4; kc++) {
            short8 bh[2], bl[2];
#pragma unroll
            for (int tj = 0; tj < 2; tj++) {
                const int ck = kc * 4 + vh * 2 + tj;
                bh[tj] = *(const short8*)(Bh + ck * 512 + ln * 8);
                bl[tj] = *(const short8*)(Bl + ck * 512 + ln * 8);
            }
            // pass-major within kc: 4 runs of 4 independent MFMAs.
            // Per-acc order per kc: av*bh, aw*bh, av*bl, aw*bl -> bit-identical.
            __builtin_amdgcn_s_setprio(1);
#pragma unroll
            for (int tj = 0; tj < 2; tj++)
#pragma unroll
                for (int ti = 0; ti < 2; ti++)
                    acc[ti][tj] = __builtin_amdgcn_mfma_f32_16x16x32_bf16(av[ti][kc], bh[tj], acc[ti][tj], 0, 0, 0);
#pragma unroll
            for (int tj = 0; tj < 2; tj++)
#pragma unroll
                for (int ti = 0; ti < 2; ti++)
                    acc[ti][tj] = __builtin_amdgcn_mfma_f32_16x16x32_bf16(aw[ti][kc], bh[tj], acc[ti][tj], 0, 0, 0);
#pragma unroll
            for (int tj = 0; tj < 2; tj++)
#pragma unroll
                for (int ti = 0; ti < 2; ti++)
                    acc[ti][tj] = __builtin_amdgcn_mfma_f32_16x16x32_bf16(av[ti][kc], bl[tj], acc[ti][tj], 0, 0, 0);
#pragma unroll
            for (int tj = 0; tj < 2; tj++)
#pragma unroll
                for (int ti = 0; ti < 2; ti++)
                    acc[ti][tj] = __builtin_amdgcn_mfma_f32_16x16x32_bf16(aw[ti][kc], bl[tj], acc[ti][tj], 0, 0, 0);
            __builtin_amdgcn_s_setprio(0);
        }

        // dist = esq - 2*dot; esq from LDS (lgkmcnt only).
        // v ascending over s/tj per lane -> strict < keeps first min
        const int v0 = (v64b + s) * 64;
#pragma unroll
        for (int tj = 0; tj < 2; tj++) {
            int vg = v0 + vh * 32 + tj * 16 + l15;
            float ev = EsqL[s * 64 + vh * 32 + tj * 16 + l15];
#pragma unroll
            for (int ti = 0; ti < 2; ti++)
#pragma unroll
                for (int r = 0; r < 4; r++) {
                    float d = fmaf(-2.f, acc[ti][tj][r], ev);
                    if (d < bD[ti][r]) { bD[ti][r] = d; bI[ti][r] = vg; }
                }
        }

        // single barrier per step: drain the in-flight stage (landed under compute),
        // then sync. After this barrier all waves are done reading buf[cur].
        __builtin_amdgcn_sched_barrier(0);
        asm volatile("s_waitcnt vmcnt(0)" ::: "memory");
        __builtin_amdgcn_sched_barrier(0);
        __builtin_amdgcn_s_barrier();
        __builtin_amdgcn_sched_barrier(0);
        cur ^= 1;
    }
#undef STAGE_STEP

    // cross-lane reduce within 16-lane groups (same q, different v), tie -> lower v
#pragma unroll
    for (int ti = 0; ti < 2; ti++)
#pragma unroll
        for (int r = 0; r < 4; r++) {
            float d = bD[ti][r];
            int   v = bI[ti][r];
#pragma unroll
            for (int m = 1; m <= 8; m <<= 1) {
                float od = __shfl_xor(d, m, 64);
                int   ov = __shfl_xor(v, m, 64);
                if (od < d || (od == d && ov < v)) { d = od; v = ov; }
            }
            if (l15 == 0) {
                int q = qb0 + qq * 32 + ti * 16 + quad * 4 + r;
                if (q < N) {
                    size_t o = (size_t)q * (vslices * 2) + blockIdx.y * 2 + vh;
                    pbD[o] = d;
                    pbI[o] = v;
                }
            }
        }
}

// ---------------- Keys cubic a=-0.5 (matches jax) ----------------
__device__ __forceinline__ float cubic_k(float x) {
    if (x <= 1.f) return (1.5f * x - 2.5f) * x * x + 1.f;
    if (x < 2.f)  return ((-0.5f * x + 2.5f) * x - 4.f) * x + 2.f;
    return 0.f;
}

// ---------------- fused argmin + upsample -> h planes ----------------
// grid = (32 b * 16 cig), 256 threads = pixel; 8 channels per thread.
// Partial-min merge over vsplit slices is parallel (all 256 threads + tree).
template <int PN>
__global__ __launch_bounds__(256)
void upsample_pack(const float* __restrict__ emb,
                   const float* __restrict__ pbD, const int* __restrict__ pbI, int vsplit,
                   short* __restrict__ hhi, short* __restrict__ hlo,
                   float* __restrict__ hfp) {
    const int t = threadIdx.x;
    const int x = t & 15, y = t >> 4;
    const int b = blockIdx.x >> 4;
    const int c0 = (blockIdx.x & 15) * 8;

    float val[8];

    if constexpr (PN == 16) {
        int q = b * 256 + t;
        float bd = pbD[(size_t)q * vsplit];
        int   bi = pbI[(size_t)q * vsplit];
        for (int j = 1; j < vsplit; j++) {
            float d  = pbD[(size_t)q * vsplit + j];
            int   i2 = pbI[(size_t)q * vsplit + j];
            if (d < bd || (d == bd && i2 < bi)) { bd = d; bi = i2; }
        }
        float4 v0 = *(const float4*)(emb + (size_t)bi * CC + c0);
        float4 v1 = *(const float4*)(emb + (size_t)bi * CC + c0 + 4);
        val[0]=v0.x; val[1]=v0.y; val[2]=v0.z; val[3]=v0.w;
        val[4]=v1.x; val[5]=v1.y; val[6]=v1.z; val[7]=v1.w;
    } else {
        constexpr int NQ = PN * PN;      // 1,4,16,64
        constexpr int KK = 256 / NQ;
        __shared__ int idxL[NQ];
        __shared__ float S[NQ][8];
        __shared__ float prd[256];
        __shared__ int   pri[256];

        // strided partial min: thread t covers query (t & NQ-1), slices t/NQ :: KK
        {
            const int qi = t & (NQ - 1);
            const int kk = t / NQ;
            float bd = INFINITY; int bi = 0;
            for (int j = kk; j < vsplit; j += KK) {
                float d  = pbD[(size_t)(b * NQ + qi) * vsplit + j];
                int   i2 = pbI[(size_t)(b * NQ + qi) * vsplit + j];
                if (d < bd || (d == bd && i2 < bi)) { bd = d; bi = i2; }
            }
            prd[t] = bd; pri[t] = bi;
        }
        __syncthreads();
        if (t < 64) {
            float d = prd[t]; int v = pri[t];
            for (int p = t + 64; p < 256; p += 64) {
                float d2 = prd[p]; int v2 = pri[p];
                if (d2 < d || (d2 == d && v2 < v)) { d = d2; v = v2; }
            }
#pragma unroll
            for (int m = NQ; m < 64; m <<= 1) {
                float d2 = __shfl_xor(d, m, 64);
                int   v2 = __shfl_xor(v, m, 64);
                if (d2 < d || (d2 == d && v2 < v)) { d = d2; v = v2; }
            }
            if (t < NQ) idxL[t] = v;
        }
        __syncthreads();
        if (t < NQ) {
            float4 v0 = *(const float4*)(emb + (size_t)idxL[t] * CC + c0);
            float4 v1 = *(const float4*)(emb + (size_t)idxL[t] * CC + c0 + 4);
            S[t][0]=v0.x; S[t][1]=v0.y; S[t][2]=v0.z; S[t][3]=v0.w;
            S[t][4]=v1.x; S[t][5]=v1.y; S[t][6]=v1.z; S[t][7]=v1.w;
        }
        __syncthreads();

        const float sc = (float)PN / 16.f;
        float sy = (y + 0.5f) * sc - 0.5f;
        float sx = (x + 0.5f) * sc - 0.5f;
        int iy0 = (int)floorf(sy) - 1;
        int ix0 = (int)floorf(sx) - 1;
        float wy[4], wx[4];
        float ssy = 0.f, ssx = 0.f;
#pragma unroll
        for (int k = 0; k < 4; k++) {
            int iy = iy0 + k, ix = ix0 + k;
            float a = (iy >= 0 && iy < PN) ? cubic_k(fabsf(sy - (float)iy)) : 0.f;
            float bb = (ix >= 0 && ix < PN) ? cubic_k(fabsf(sx - (float)ix)) : 0.f;
            wy[k] = a; ssy += a;
            wx[k] = bb; ssx += bb;
        }
        float ry = 1.f / ssy, rx = 1.f / ssx;
#pragma unroll
        for (int k = 0; k < 4; k++) { wy[k] *= ry; wx[k] *= rx; }

#pragma unroll
        for (int j = 0; j < 8; j++) val[j] = 0.f;
#pragma unroll
        for (int k4 = 0; k4 < 4; k4++) {
            int iy = iy0 + k4;
            if (iy < 0 || iy >= PN) continue;
#pragma unroll
            for (int j4 = 0; j4 < 4; j4++) {
                int ix = ix0 + j4;
                if (ix < 0 || ix >= PN) continue;
                float w = wy[k4] * wx[j4];
                const float* sp = S[iy * PN + ix];
#pragma unroll
                for (int j = 0; j < 8; j++) val[j] = fmaf(w, sp[j], val[j]);
            }
        }
    }

    short hs[8], ls[8];
#pragma unroll
    for (int j = 0; j < 8; j++) {
        uint32_t u = pack_hilo(val[j]);
        hs[j] = (short)(u >> 16);
        ls[j] = (short)(u & 0xffffu);
    }
    size_t ho = ((size_t)(b * 18 + y + 1) * 18 + (x + 1)) * CC + c0;
    *(short8*)(hhi + ho) = *(short8*)hs;
    *(short8*)(hlo + ho) = *(short8*)ls;
#pragma unroll
    for (int j = 0; j < 8; j++)
        hfp[((size_t)b * CC + c0 + j) * 256 + t] = val[j];
}

// ---------------- MFMA conv3x3: LDS weights, T14 async-split staging ----------------
template <bool FIRST>
__global__ __launch_bounds__(256)
void conv_mfma(const short* __restrict__ Whi, const short* __restrict__ Wlo,
               const short* __restrict__ hhi, const short* __restrict__ hlo,
               const float* __restrict__ hfp, const float* __restrict__ pb,
               const float* __restrict__ f, float* __restrict__ f_hat,
               float* __restrict__ lacc, int kphi) {
    __shared__ short Bsh[64 * CSTR];
    __shared__ short Bsl[64 * CSTR];
    __shared__ float red[2][16][65];
    __shared__ float lred[2];

    const int t = threadIdx.x;
    const int wave = t >> 6, lane = t & 63;
    const int quad = lane >> 4, l15 = lane & 15;
    const int pxg = wave & 1, kh = wave >> 1;
    const int cH = blockIdx.x & 1;
    const int pc = blockIdx.x >> 1;
    const int b = pc >> 3;
    const int pxbase = (pc & 7) * 32;
    const int pa = pxbase + pxg * 16 + l15;
    const int ya = pa >> 4, xa = pa & 15;

    floatx4 acc[4];
    floatx4 z = {0.f, 0.f, 0.f, 0.f};
#pragma unroll
    for (int nt = 0; nt < 4; nt++) acc[nt] = z;

    // per-thread staging slice: 4 chunks x 2 planes = 8 short8 in regs
    const int srow = t >> 4, scol = (t & 15) * 8;   // chunk i covers row srow + i*16
    short8 rh[4], rl[4];
    {
        const short* gh = Whi + ((size_t)(kphi * 9 + 0) * CC + cH * 64) * CC;
        const short* gl = Wlo + ((size_t)(kphi * 9 + 0) * CC + cH * 64) * CC;
#pragma unroll
        for (int i = 0; i < 4; i++) {
            rh[i] = *(const short8*)(gh + (srow + i * 16) * CC + scol);
            rl[i] = *(const short8*)(gl + (srow + i * 16) * CC + scol);
        }
    }

    for (int kk = 0; kk < 9; kk++) {
        __syncthreads();          // all waves done reading previous kk's weights
#pragma unroll
        for (int i = 0; i < 4; i++) {
            *(short8*)&Bsh[(srow + i * 16) * CSTR + scol] = rh[i];
            *(short8*)&Bsl[(srow + i * 16) * CSTR + scol] = rl[i];
        }
        __syncthreads();          // writes visible

        // preload kk+1 weights to regs; latency hides under this kk's MFMAs
        if (kk < 8) {
            const short* gh = Whi + ((size_t)(kphi * 9 + kk + 1) * CC + cH * 64) * CC;
            const short* gl = Wlo + ((size_t)(kphi * 9 + kk + 1) * CC + cH * 64) * CC;
#pragma unroll
            for (int i = 0; i < 4; i++) {
                rh[i] = *(const short8*)(gh + (srow + i * 16) * CC + scol);
                rl[i] = *(const short8*)(gl + (srow + i * 16) * CC + scol);
            }
        }

        const int ky = kk / 3, kx = kk % 3;
        const size_t aoff = ((size_t)(b * 18 + ya + ky) * 18 + (xa + kx)) * CC + quad * 8;
#pragma unroll
        for (int i2 = 0; i2 < 2; i2++) {
            const int cic = kh * 2 + i2;
            short8 ah = *(const short8*)(hhi + aoff + cic * 32);
            short8 al = *(const short8*)(hlo + aoff + cic * 32);
#pragma unroll
            for (int nt = 0; nt < 4; nt++) {
                short8 bh = *(const short8*)&Bsh[(nt * 16 + l15) * CSTR + cic * 32 + quad * 8];
                short8 bl = *(const short8*)&Bsl[(nt * 16 + l15) * CSTR + cic * 32 + quad * 8];
                acc[nt] = __builtin_amdgcn_mfma_f32_16x16x32_bf16(ah, bh, acc[nt], 0, 0, 0);
                acc[nt] = __builtin_amdgcn_mfma_f32_16x16x32_bf16(al, bh, acc[nt], 0, 0, 0);
                acc[nt] = __builtin_amdgcn_mfma_f32_16x16x32_bf16(ah, bl, acc[nt], 0, 0, 0);
            }
        }
    }

    __syncthreads();
    if (kh == 1) {
#pragma unroll
        for (int nt = 0; nt < 4; nt++)
#pragma unroll
            for (int r = 0; r < 4; r++)
                red[pxg][quad * 4 + r][nt * 16 + l15] = acc[nt][r];
    }
    __syncthreads();

    if (kh == 0) {
        const int pe = pxbase + pxg * 16 + quad * 4;
        float lsum = 0.f;
#pragma unroll
        for (int nt = 0; nt < 4; nt++) {
            int cout = cH * 64 + nt * 16 + l15;
            float bias = pb[kphi * CC + cout];
            size_t gi = ((size_t)b * CC + cout) * 256 + pe;
            float4 h4  = *(const float4*)(hfp + gi);
            float4 f4  = *(const float4*)(f + gi);
            float4 fh4 = FIRST ? make_float4(0.f, 0.f, 0.f, 0.f) : *(const float4*)(f_hat + gi);
            float c0 = acc[nt][0] + red[pxg][quad * 4 + 0][nt * 16 + l15] + bias;
            float c1 = acc[nt][1] + red[pxg][quad * 4 + 1][nt * 16 + l15] + bias;
            float c2 = acc[nt][2] + red[pxg][quad * 4 + 2][nt * 16 + l15] + bias;
            float c3 = acc[nt][3] + red[pxg][quad * 4 + 3][nt * 16 + l15] + bias;
            float o0 = fh4.x + 0.5f * h4.x + 0.5f * c0;
            float o1 = fh4.y + 0.5f * h4.y + 0.5f * c1;
            float o2 = fh4.z + 0.5f * h4.z + 0.5f * c2;
            float o3 = fh4.w + 0.5f * h4.w + 0.5f * c3;
            *(float4*)(f_hat + gi) = make_float4(o0, o1, o2, o3);
            float d0 = o0 - f4.x, d1 = o1 - f4.y, d2 = o2 - f4.z, d3 = o3 - f4.w;
            lsum += d0*d0 + d1*d1 + d2*d2 + d3*d3;
        }
#pragma unroll
        for (int off = 32; off; off >>= 1) lsum += __shfl_down(lsum, off, 64);
        if (lane == 0) lred[pxg] = lsum;
    }
    __syncthreads();
    if (t == 0) atomicAdd(lacc, lred[0] + lred[1]);
}

__global__ void finalize_kernel(const float* __restrict__ lacc, float* __restrict__ out_loss) {
    *out_loss = lacc[0] * (0.25f / (float)NELEM);   // (1+BETA)/SN * sum of means
}

extern "C" void kernel_launch(void* const* d_in, const int* in_sizes, int n_in,
                              void* d_out, int out_size, void* d_ws, size_t ws_size,
                              hipStream_t stream) {
    const float* f   = (const float*)d_in[0];
    const float* emb = (const float*)d_in[1];
    const float* pw  = (const float*)d_in[2];
    const float* pb  = (const float*)d_in[3];
    float* out = (float*)d_out;

    uint32_t* w32 = (uint32_t*)d_ws;
    short* rphi = (short*)(w32);                    // 1,048,576 shorts
    short* rplo = (short*)(w32 + 524288);
    short* ephi = (short*)(w32 + 1048576);          // 1,048,576 shorts
    short* eplo = (short*)(w32 + 1572864);
    short* Whi  = (short*)(w32 + 2097152);          // 589,824 shorts
    short* Wlo  = (short*)(w32 + 2392064);
    short* hhi  = (short*)(w32 + 2686976);          // 1,327,104 shorts
    short* hlo  = (short*)(w32 + 3350528);
    float* hfp  = (float*)(w32 + 4014080);          // 1,048,576 f
    float* esq  = (float*)(w32 + 5062656);          // 8192
    float* pbD  = (float*)(w32 + 5070848);          // 262144
    int*   pbI  = (int*)  (w32 + 5332992);          // 262144
    float* lacc = (float*)(w32 + 5595136);          // 1

    // zero halos of h planes (hhi & hlo contiguous)
    hipMemsetAsync(hhi, 0, (size_t)2 * 1327104 * sizeof(short), stream);

    esq_pack<<<512, 256, 0, stream>>>(emb, esq, ephi, eplo, lacc);
    prepack_w<<<256, 256, 0, stream>>>(pw, Whi, Wlo);

    // mirror np.linspace(1/12, 11/12, 4) exactly in float64
    double start = 1.0 / 12.0;
    double stop  = 1.0 - 1.0 / 12.0;
    double step  = (stop - start) / 3.0;
    double ticks[4] = {start, 1.0 * step + start, 2.0 * step + start, stop};

    const int pns[5]    = {1, 2, 4, 8, 16};
    const int qb5[5]    = {1, 1, 4, 16, 64};        // ceil(N/128)
    const int vs5[5]    = {128, 128, 128, 32, 8};   // vslices (x st64 x 64 = 8192)
    const int st5[5]    = {1, 1, 1, 4, 16};         // 64-v steps per block
    const int pgrid5[5] = {1024, 1024, 1024, 1024, 4096};   // pool_pack grids

    for (int si = 0; si < 5; si++) {
        int pn = pns[si];
        int N  = BB * pn * pn;
        double tt = (double)si / 4.0;
        int kphi = 0;
        double bd = fabs(ticks[0] - tt);
        for (int i = 1; i < 4; i++) {
            double d = fabs(ticks[i] - tt);
            if (d < bd) { bd = d; kphi = i; }   // np.argmin: first occurrence
        }

        switch (pn) {
            case 1:  pool_pack<1,  true ><<<pgrid5[si], 256, 0, stream>>>(f, out, rphi, rplo); break;
            case 2:  pool_pack<2,  false><<<pgrid5[si], 256, 0, stream>>>(f, out, rphi, rplo); break;
            case 4:  pool_pack<4,  false><<<pgrid5[si], 256, 0, stream>>>(f, out, rphi, rplo); break;
            case 8:  pool_pack<8,  false><<<pgrid5[si], 256, 0, stream>>>(f, out, rphi, rplo); break;
            default: pool_pack<16, false><<<pgrid5[si], 256, 0, stream>>>(f, out, rphi, rplo); break;
        }

        dim3 dgrid(qb5[si], vs5[si]);
        dist_mfma<<<dgrid, 512, 0, stream>>>(rphi, rplo, ephi, eplo, esq, pbD, pbI, N, st5[si]);

        int vsplit = vs5[si] * 2;
        switch (pn) {
            case 1:  upsample_pack<1><<<512, 256, 0, stream>>>(emb, pbD, pbI, vsplit, hhi, hlo, hfp); break;
            case 2:  upsample_pack<2><<<512, 256, 0, stream>>>(emb, pbD, pbI, vsplit, hhi, hlo, hfp); break;
            case 4:  upsample_pack<4><<<512, 256, 0, stream>>>(emb, pbD, pbI, vsplit, hhi, hlo, hfp); break;
            case 8:  upsample_pack<8><<<512, 256, 0, stream>>>(emb, pbD, pbI, vsplit, hhi, hlo, hfp); break;
            default: upsample_pack<16><<<512, 256, 0, stream>>>(emb, pbD, pbI, vsplit, hhi, hlo, hfp); break;
        }

        if (si == 0) conv_mfma<true><<<512, 256, 0, stream>>>(Whi, Wlo, hhi, hlo, hfp, pb, f, out, lacc, kphi);
        else         conv_mfma<false><<<512, 256, 0, stream>>>(Whi, Wlo, hhi, hlo, hfp, pb, f, out, lacc, kphi);
    }

    finalize_kernel<<<1, 1, 0, stream>>>(lacc, out + NELEM);
}

// Round 13
// 384.568 us; speedup vs baseline: 1.1315x; 1.0212x over previous
//
#include <hip/hip_runtime.h>
#include <math.h>

#define CC   128
#define HH   16
#define WW   16
#define BB   32
#define VV   8192
#define NELEM (BB*CC*HH*WW)   // 1,048,576

typedef short short8 __attribute__((ext_vector_type(8)));
typedef float floatx4 __attribute__((ext_vector_type(4)));

#define CSTR 136   // conv LDS row stride in bf16 elems (128 + 8 pad)

// address-space helpers for global_load_lds
typedef __attribute__((address_space(1))) void as1_void;
typedef __attribute__((address_space(3))) void as3_void;

__device__ __forceinline__ void gl_lds16(const void* g, void* l) {
    // LDS dest is wave-uniform base; HW adds lane*16. Global src is per-lane.
    __builtin_amdgcn_global_load_lds((as1_void*)g, (as3_void*)l, 16, 0, 0);
}

// ---------------- hi/lo bf16 split pack (RNE both) ----------------
__device__ __forceinline__ uint32_t pack_hilo(float x) {
    uint32_t u = __float_as_uint(x);
    uint32_t hb = (u + 0x7fffu + ((u >> 16) & 1u)) & 0xffff0000u;
    float hf = __uint_as_float(hb);
    float lo = x - hf;
    uint32_t ul = __float_as_uint(lo);
    uint32_t lb = ((ul + 0x7fffu + ((ul >> 16) & 1u)) >> 16) & 0xffffu;
    return hb | lb;
}

// ---------------- e_sq + codebook hi/lo plane split + lacc zero ----------------
// 131072 threads: 16 per codebook row.
// ephi/eplo are written in MFMA-fragment order per 128-row vtile:
//   elem (v, c): vt=v>>7, vr=v&127, vh=vr>>6, tj=(vr>>4)&3, l15=vr&15,
//                kc=c>>5, quad=(c>>3)&3, e=c&7
//   off = vt*16384 + ((kc*8 + vh*4 + tj)*64 + quad*16 + l15)*8 + e
// A 64-v half-tile (vt, half) is the 16 chunks {kc*8 + half*4 + g16}, each 1KB.
__global__ void esq_pack(const float* __restrict__ emb, float* __restrict__ esq,
                         short* __restrict__ ephi, short* __restrict__ eplo,
                         float* __restrict__ lacc) {
    int t = blockIdx.x * 256 + threadIdx.x;
    int v = t >> 4, g = t & 15;
    const float* row = emb + (size_t)v * CC + g * 8;
    float4 a = *(const float4*)row;
    float4 b = *(const float4*)(row + 4);
    float s = a.x*a.x + a.y*a.y + a.z*a.z + a.w*a.w
            + b.x*b.x + b.y*b.y + b.z*b.z + b.w*b.w;
    s += __shfl_xor(s, 1, 64);
    s += __shfl_xor(s, 2, 64);
    s += __shfl_xor(s, 4, 64);
    s += __shfl_xor(s, 8, 64);
    if (g == 0) esq[v] = s;
    float vals[8] = {a.x, a.y, a.z, a.w, b.x, b.y, b.z, b.w};
    short hs[8], ls[8];
#pragma unroll
    for (int j = 0; j < 8; j++) {
        uint32_t u = pack_hilo(vals[j]);
        hs[j] = (short)(u >> 16);
        ls[j] = (short)(u & 0xffffu);
    }
    int vt = v >> 7, vr = v & 127;
    int vh = vr >> 6, tj = (vr >> 4) & 3, r15 = vr & 15;
    int kc = g >> 2, quad = g & 3;
    size_t off = (size_t)vt * 16384 + (size_t)((kc * 8 + vh * 4 + tj) * 64 + quad * 16 + r15) * 8;
    *(short8*)(ephi + off) = *(short8*)hs;
    *(short8*)(eplo + off) = *(short8*)ls;
    if (t == 0) lacc[0] = 0.f;
}

// ---------------- pre-transpose + split conv weights: Wt[kphi][kk][cout][cin] ----------------
__global__ void prepack_w(const float* __restrict__ pw, short* __restrict__ Whi,
                          short* __restrict__ Wlo) {
    int id = blockIdx.x * 256 + threadIdx.x;      // 65536 = 4*128*128
    int ci = id & 127, cout = (id >> 7) & 127, kp = id >> 14;
    const float* src = pw + ((size_t)(kp * CC + cout) * CC + ci) * 9;
#pragma unroll
    for (int kk = 0; kk < 9; kk++) {
        uint32_t u = pack_hilo(src[kk]);
        size_t o = ((size_t)(kp * 9 + kk) * CC + cout) * CC + ci;
        Whi[o] = (short)(u >> 16);
        Wlo[o] = (short)(u & 0xffffu);
    }
}

// ---------------- pooled residual (f - f_hat) -> hi/lo planes, PARALLEL ----------------
// Every thread reads exactly 4 f elements; outputs reduced by a T-lane shuffle tree.
// PN=1: T=64 (full 16x16 window/wave), PN=2: T=16, PN=4: T=4 (one float4/thread),
// PN=8: T=1 (sequential 2x2, BIT-IDENTICAL to original), PN=16: original 1-elem path.
template <int PN, bool FIRSTP>
__global__ __launch_bounds__(256)
void pool_pack(const float* __restrict__ f, const float* __restrict__ fh,
               short* __restrict__ rh, short* __restrict__ rl) {
    const int tid = threadIdx.x;
    const int gid = blockIdx.x * 256 + tid;

    if constexpr (PN == 16) {
        int c = gid % CC;
        int n = gid / CC;
        int px = n % 16, py = (n / 16) % 16, b = n / 256;
        size_t o = (((size_t)b * CC + c) * HH + py) * WW + px;
        float acc = FIRSTP ? f[o] : (f[o] - fh[o]);
        uint32_t u = pack_hilo(acc);
        rh[gid] = (short)(u >> 16);
        rl[gid] = (short)(u & 0xffffu);
        return;
    } else if constexpr (PN == 8) {
        // 2x2 window, sequential order identical to original
        int c = gid & 127;
        int n = gid >> 7;
        int px = n & 7, py = (n >> 3) & 7, b = n >> 6;
        size_t o = (((size_t)b * CC + c) * HH + py * 2) * WW + px * 2;
        float acc = 0.f;
        acc += FIRSTP ? f[o]      : (f[o]      - fh[o]);
        acc += FIRSTP ? f[o + 1]  : (f[o + 1]  - fh[o + 1]);
        acc += FIRSTP ? f[o + 16] : (f[o + 16] - fh[o + 16]);
        acc += FIRSTP ? f[o + 17] : (f[o + 17] - fh[o + 17]);
        uint32_t u = pack_hilo(acc * 0.25f);
        rh[gid] = (short)(u >> 16);
        rl[gid] = (short)(u & 0xffffu);
        return;
    } else {
        constexpr int T = (PN == 1) ? 64 : (PN == 2) ? 16 : 4;   // lanes per output
        const int out = gid / T;
        const int sub = tid & (T - 1);
        const int c = out & 127;
        const int n = out >> 7;
        const int px = n % PN, py = (n / PN) % PN, b = n / (PN * PN);
        constexpr int S = 16 / PN;                // window side
        // layout: thread sub -> row = sub / (S/4), col4 = (sub % (S/4)) * 4
        const int row = sub / (S / 4);
        const int col4 = (sub % (S / 4)) * 4;
        size_t o = (((size_t)b * CC + c) * HH + py * S + row) * WW + px * S + col4;
        float4 a = *(const float4*)(f + o);
        float sum;
        if (FIRSTP) {
            sum = a.x; sum += a.y; sum += a.z; sum += a.w;
        } else {
            float4 h = *(const float4*)(fh + o);
            sum = (a.x - h.x); sum += (a.y - h.y); sum += (a.z - h.z); sum += (a.w - h.w);
        }
#pragma unroll
        for (int m = 1; m < T; m <<= 1) sum += __shfl_xor(sum, m, 64);
        if (sub == 0) {
            uint32_t u = pack_hilo(sum * (1.f / (float)(S * S)));
            rh[out] = (short)(u >> 16);
            rl[out] = (short)(u & 0xffffu);
        }
    }
}

// ---------------- MFMA distance v17: v16 with 3-pass hi/lo (ll dropped) ----------------
// dot ~= av*bh + aw*bh + av*bl (drops aw*bl, magnitude ~2^-18 |a||b| -> ~4e-6 relative
// on the dot, same order as the hi/lo representation error already carried vs fp32;
// conv_mfma has always used the same 3-pass scheme). 25% fewer MFMAs.
// ABSMAX IS THE FLIP DETECTOR: any change from 0.0078125 -> revert to 4-pass.
__global__ __launch_bounds__(512, 4)
void dist_mfma(const short* __restrict__ rphi, const short* __restrict__ rplo,
               const short* __restrict__ ephi, const short* __restrict__ eplo,
               const float* __restrict__ esq,
               float* __restrict__ pbD, int* __restrict__ pbI,
               int N, int st64) {
    __shared__ short Bs[2][2][8192];       // [dbuf][hi/lo][64-v step, chunks kc*4+g16]
    __shared__ float EsqL[1024];           // esq slice (<= 16 steps * 64)

    const int tid  = threadIdx.x;
    const int wave = tid >> 6, ln = tid & 63;
    const int quad = ln >> 4, l15 = ln & 15;
    const int qq = wave & 3, vh = wave >> 2;
    const int qb0 = blockIdx.x * 128;
    const int vslices = gridDim.y;
    const int v64b = blockIdx.y * st64;    // base in 64-v units
    const int nsteps = st64;

// stage 64-v half-tile (v64b+s): vt=(v64b+s)>>1, hf=(v64b+s)&1; 16 chunks of 1KB/plane
#define STAGE_STEP(buf_, s_) do {                                                    \
        const int h_  = v64b + (s_);                                                 \
        const int vt_ = h_ >> 1, hf_ = h_ & 1;                                       \
        _Pragma("unroll")                                                            \
        for (int i_ = 0; i_ < 2; i_++) {                                             \
            const int ck_ = wave * 2 + i_;                                           \
            const int kc_ = ck_ >> 2, g_ = ck_ & 3;                                  \
            const size_t so_ = (size_t)vt_ * 32768 +                                 \
                               (size_t)(kc_ * 8 + hf_ * 4 + g_) * 1024;              \
            gl_lds16((const char*)ephi + so_ + ln * 16, (char*)&Bs[(buf_)][0][0] + ck_ * 1024); \
            gl_lds16((const char*)eplo + so_ + ln * 16, (char*)&Bs[(buf_)][1][0] + ck_ * 1024); \
        } } while (0)

    // prologue: stage step 0, the esq slice, and A frags; full drain + barrier once
    STAGE_STEP(0, 0);
    {
        int echunks = (st64 * 256 + 1023) >> 10;   // 1KB chunks of esq slice bytes
        if (wave < echunks)
            gl_lds16((const char*)(esq + v64b * 64) + wave * 1024 + ln * 16,
                     (char*)EsqL + wave * 1024);
    }

    // A fragments loaded once: 32 q per wave (rows may exceed N: garbage but finite;
    // outputs guarded). 16 short8 = 64 VGPRs.
    short8 av[2][4], aw[2][4];
#pragma unroll
    for (int ti = 0; ti < 2; ti++) {
        const size_t arow = (size_t)(qb0 + qq * 32 + ti * 16 + l15) * CC + quad * 8;
#pragma unroll
        for (int kc = 0; kc < 4; kc++) {
            av[ti][kc] = *(const short8*)(rphi + arow + kc * 32);
            aw[ti][kc] = *(const short8*)(rplo + arow + kc * 32);
        }
    }
    __builtin_amdgcn_sched_barrier(0);
    asm volatile("s_waitcnt vmcnt(0)" ::: "memory");   // stage0 + esq + A resident
    __builtin_amdgcn_sched_barrier(0);
    __builtin_amdgcn_s_barrier();
    __builtin_amdgcn_sched_barrier(0);

    float bD[2][4];
    int   bI[2][4];
#pragma unroll
    for (int ti = 0; ti < 2; ti++)
#pragma unroll
        for (int r = 0; r < 4; r++) { bD[ti][r] = INFINITY; bI[ti][r] = 0; }

    int cur = 0;
    for (int s = 0; s < nsteps; s++) {
        // issue next-step stage first; it lands during this step's compute
        if (s + 1 < nsteps) STAGE_STEP(cur ^ 1, s + 1);
        __builtin_amdgcn_sched_barrier(0);   // pin stage issue before compute

        floatx4 acc[2][2];
        floatx4 z = {0.f, 0.f, 0.f, 0.f};
#pragma unroll
        for (int ti = 0; ti < 2; ti++)
#pragma unroll
            for (int tj = 0; tj < 2; tj++) acc[ti][tj] = z;

        // fragment reads: chunk (kc*4 + vh*2 + tj)*1024B + lane*16B -> conflict-free linear
        const short* Bh = &Bs[cur][0][0];
        const short* Bl = &Bs[cur][1][0];
#pragma unroll
        for (int kc = 0; kc < 4; kc++) {
            short8 bh[2], bl[2];
#pragma unroll
            for (int tj = 0; tj < 2; tj++) {
                const int ck = kc * 4 + vh * 2 + tj;
                bh[tj] = *(const short8*)(Bh + ck * 512 + ln * 8);
                bl[tj] = *(const short8*)(Bl + ck * 512 + ln * 8);
            }
            // 3-pass per kc: av*bh, aw*bh, av*bl (ll dropped; conv has always done this)
            __builtin_amdgcn_s_setprio(1);
#pragma unroll
            for (int tj = 0; tj < 2; tj++)
#pragma unroll
                for (int ti = 0; ti < 2; ti++)
                    acc[ti][tj] = __builtin_amdgcn_mfma_f32_16x16x32_bf16(av[ti][kc], bh[tj], acc[ti][tj], 0, 0, 0);
#pragma unroll
            for (int tj = 0; tj < 2; tj++)
#pragma unroll
                for (int ti = 0; ti < 2; ti++)
                    acc[ti][tj] = __builtin_amdgcn_mfma_f32_16x16x32_bf16(aw[ti][kc], bh[tj], acc[ti][tj], 0, 0, 0);
#pragma unroll
            for (int tj = 0; tj < 2; tj++)
#pragma unroll
                for (int ti = 0; ti < 2; ti++)
                    acc[ti][tj] = __builtin_amdgcn_mfma_f32_16x16x32_bf16(av[ti][kc], bl[tj], acc[ti][tj], 0, 0, 0);
            __builtin_amdgcn_s_setprio(0);
        }

        // dist = esq - 2*dot; esq from LDS (lgkmcnt only).
        // v ascending over s/tj per lane -> strict < keeps first min
        const int v0 = (v64b + s) * 64;
#pragma unroll
        for (int tj = 0; tj < 2; tj++) {
            int vg = v0 + vh * 32 + tj * 16 + l15;
            float ev = EsqL[s * 64 + vh * 32 + tj * 16 + l15];
#pragma unroll
            for (int ti = 0; ti < 2; ti++)
#pragma unroll
                for (int r = 0; r < 4; r++) {
                    float d = fmaf(-2.f, acc[ti][tj][r], ev);
                    if (d < bD[ti][r]) { bD[ti][r] = d; bI[ti][r] = vg; }
                }
        }

        // single barrier per step: drain the in-flight stage (landed under compute),
        // then sync. After this barrier all waves are done reading buf[cur].
        __builtin_amdgcn_sched_barrier(0);
        asm volatile("s_waitcnt vmcnt(0)" ::: "memory");
        __builtin_amdgcn_sched_barrier(0);
        __builtin_amdgcn_s_barrier();
        __builtin_amdgcn_sched_barrier(0);
        cur ^= 1;
    }
#undef STAGE_STEP

    // cross-lane reduce within 16-lane groups (same q, different v), tie -> lower v
#pragma unroll
    for (int ti = 0; ti < 2; ti++)
#pragma unroll
        for (int r = 0; r < 4; r++) {
            float d = bD[ti][r];
            int   v = bI[ti][r];
#pragma unroll
            for (int m = 1; m <= 8; m <<= 1) {
                float od = __shfl_xor(d, m, 64);
                int   ov = __shfl_xor(v, m, 64);
                if (od < d || (od == d && ov < v)) { d = od; v = ov; }
            }
            if (l15 == 0) {
                int q = qb0 + qq * 32 + ti * 16 + quad * 4 + r;
                if (q < N) {
                    size_t o = (size_t)q * (vslices * 2) + blockIdx.y * 2 + vh;
                    pbD[o] = d;
                    pbI[o] = v;
                }
            }
        }
}

// ---------------- Keys cubic a=-0.5 (matches jax) ----------------
__device__ __forceinline__ float cubic_k(float x) {
    if (x <= 1.f) return (1.5f * x - 2.5f) * x * x + 1.f;
    if (x < 2.f)  return ((-0.5f * x + 2.5f) * x - 4.f) * x + 2.f;
    return 0.f;
}

// ---------------- fused argmin + upsample -> h planes ----------------
// grid = (32 b * 16 cig), 256 threads = pixel; 8 channels per thread.
// Partial-min merge over vsplit slices is parallel (all 256 threads + tree).
template <int PN>
__global__ __launch_bounds__(256)
void upsample_pack(const float* __restrict__ emb,
                   const float* __restrict__ pbD, const int* __restrict__ pbI, int vsplit,
                   short* __restrict__ hhi, short* __restrict__ hlo,
                   float* __restrict__ hfp) {
    const int t = threadIdx.x;
    const int x = t & 15, y = t >> 4;
    const int b = blockIdx.x >> 4;
    const int c0 = (blockIdx.x & 15) * 8;

    float val[8];

    if constexpr (PN == 16) {
        int q = b * 256 + t;
        float bd = pbD[(size_t)q * vsplit];
        int   bi = pbI[(size_t)q * vsplit];
        for (int j = 1; j < vsplit; j++) {
            float d  = pbD[(size_t)q * vsplit + j];
            int   i2 = pbI[(size_t)q * vsplit + j];
            if (d < bd || (d == bd && i2 < bi)) { bd = d; bi = i2; }
        }
        float4 v0 = *(const float4*)(emb + (size_t)bi * CC + c0);
        float4 v1 = *(const float4*)(emb + (size_t)bi * CC + c0 + 4);
        val[0]=v0.x; val[1]=v0.y; val[2]=v0.z; val[3]=v0.w;
        val[4]=v1.x; val[5]=v1.y; val[6]=v1.z; val[7]=v1.w;
    } else {
        constexpr int NQ = PN * PN;      // 1,4,16,64
        constexpr int KK = 256 / NQ;
        __shared__ int idxL[NQ];
        __shared__ float S[NQ][8];
        __shared__ float prd[256];
        __shared__ int   pri[256];

        // strided partial min: thread t covers query (t & NQ-1), slices t/NQ :: KK
        {
            const int qi = t & (NQ - 1);
            const int kk = t / NQ;
            float bd = INFINITY; int bi = 0;
            for (int j = kk; j < vsplit; j += KK) {
                float d  = pbD[(size_t)(b * NQ + qi) * vsplit + j];
                int   i2 = pbI[(size_t)(b * NQ + qi) * vsplit + j];
                if (d < bd || (d == bd && i2 < bi)) { bd = d; bi = i2; }
            }
            prd[t] = bd; pri[t] = bi;
        }
        __syncthreads();
        if (t < 64) {
            float d = prd[t]; int v = pri[t];
            for (int p = t + 64; p < 256; p += 64) {
                float d2 = prd[p]; int v2 = pri[p];
                if (d2 < d || (d2 == d && v2 < v)) { d = d2; v = v2; }
            }
#pragma unroll
            for (int m = NQ; m < 64; m <<= 1) {
                float d2 = __shfl_xor(d, m, 64);
                int   v2 = __shfl_xor(v, m, 64);
                if (d2 < d || (d2 == d && v2 < v)) { d = d2; v = v2; }
            }
            if (t < NQ) idxL[t] = v;
        }
        __syncthreads();
        if (t < NQ) {
            float4 v0 = *(const float4*)(emb + (size_t)idxL[t] * CC + c0);
            float4 v1 = *(const float4*)(emb + (size_t)idxL[t] * CC + c0 + 4);
            S[t][0]=v0.x; S[t][1]=v0.y; S[t][2]=v0.z; S[t][3]=v0.w;
            S[t][4]=v1.x; S[t][5]=v1.y; S[t][6]=v1.z; S[t][7]=v1.w;
        }
        __syncthreads();

        const float sc = (float)PN / 16.f;
        float sy = (y + 0.5f) * sc - 0.5f;
        float sx = (x + 0.5f) * sc - 0.5f;
        int iy0 = (int)floorf(sy) - 1;
        int ix0 = (int)floorf(sx) - 1;
        float wy[4], wx[4];
        float ssy = 0.f, ssx = 0.f;
#pragma unroll
        for (int k = 0; k < 4; k++) {
            int iy = iy0 + k, ix = ix0 + k;
            float a = (iy >= 0 && iy < PN) ? cubic_k(fabsf(sy - (float)iy)) : 0.f;
            float bb = (ix >= 0 && ix < PN) ? cubic_k(fabsf(sx - (float)ix)) : 0.f;
            wy[k] = a; ssy += a;
            wx[k] = bb; ssx += bb;
        }
        float ry = 1.f / ssy, rx = 1.f / ssx;
#pragma unroll
        for (int k = 0; k < 4; k++) { wy[k] *= ry; wx[k] *= rx; }

#pragma unroll
        for (int j = 0; j < 8; j++) val[j] = 0.f;
#pragma unroll
        for (int k4 = 0; k4 < 4; k4++) {
            int iy = iy0 + k4;
            if (iy < 0 || iy >= PN) continue;
#pragma unroll
            for (int j4 = 0; j4 < 4; j4++) {
                int ix = ix0 + j4;
                if (ix < 0 || ix >= PN) continue;
                float w = wy[k4] * wx[j4];
                const float* sp = S[iy * PN + ix];
#pragma unroll
                for (int j = 0; j < 8; j++) val[j] = fmaf(w, sp[j], val[j]);
            }
        }
    }

    short hs[8], ls[8];
#pragma unroll
    for (int j = 0; j < 8; j++) {
        uint32_t u = pack_hilo(val[j]);
        hs[j] = (short)(u >> 16);
        ls[j] = (short)(u & 0xffffu);
    }
    size_t ho = ((size_t)(b * 18 + y + 1) * 18 + (x + 1)) * CC + c0;
    *(short8*)(hhi + ho) = *(short8*)hs;
    *(short8*)(hlo + ho) = *(short8*)ls;
#pragma unroll
    for (int j = 0; j < 8; j++)
        hfp[((size_t)b * CC + c0 + j) * 256 + t] = val[j];
}

// ---------------- MFMA conv3x3: LDS weights, T14 async-split staging ----------------
template <bool FIRST>
__global__ __launch_bounds__(256)
void conv_mfma(const short* __restrict__ Whi, const short* __restrict__ Wlo,
               const short* __restrict__ hhi, const short* __restrict__ hlo,
               const float* __restrict__ hfp, const float* __restrict__ pb,
               const float* __restrict__ f, float* __restrict__ f_hat,
               float* __restrict__ lacc, int kphi) {
    __shared__ short Bsh[64 * CSTR];
    __shared__ short Bsl[64 * CSTR];
    __shared__ float red[2][16][65];
    __shared__ float lred[2];

    const int t = threadIdx.x;
    const int wave = t >> 6, lane = t & 63;
    const int quad = lane >> 4, l15 = lane & 15;
    const int pxg = wave & 1, kh = wave >> 1;
    const int cH = blockIdx.x & 1;
    const int pc = blockIdx.x >> 1;
    const int b = pc >> 3;
    const int pxbase = (pc & 7) * 32;
    const int pa = pxbase + pxg * 16 + l15;
    const int ya = pa >> 4, xa = pa & 15;

    floatx4 acc[4];
    floatx4 z = {0.f, 0.f, 0.f, 0.f};
#pragma unroll
    for (int nt = 0; nt < 4; nt++) acc[nt] = z;

    // per-thread staging slice: 4 chunks x 2 planes = 8 short8 in regs
    const int srow = t >> 4, scol = (t & 15) * 8;   // chunk i covers row srow + i*16
    short8 rh[4], rl[4];
    {
        const short* gh = Whi + ((size_t)(kphi * 9 + 0) * CC + cH * 64) * CC;
        const short* gl = Wlo + ((size_t)(kphi * 9 + 0) * CC + cH * 64) * CC;
#pragma unroll
        for (int i = 0; i < 4; i++) {
            rh[i] = *(const short8*)(gh + (srow + i * 16) * CC + scol);
            rl[i] = *(const short8*)(gl + (srow + i * 16) * CC + scol);
        }
    }

    for (int kk = 0; kk < 9; kk++) {
        __syncthreads();          // all waves done reading previous kk's weights
#pragma unroll
        for (int i = 0; i < 4; i++) {
            *(short8*)&Bsh[(srow + i * 16) * CSTR + scol] = rh[i];
            *(short8*)&Bsl[(srow + i * 16) * CSTR + scol] = rl[i];
        }
        __syncthreads();          // writes visible

        // preload kk+1 weights to regs; latency hides under this kk's MFMAs
        if (kk < 8) {
            const short* gh = Whi + ((size_t)(kphi * 9 + kk + 1) * CC + cH * 64) * CC;
            const short* gl = Wlo + ((size_t)(kphi * 9 + kk + 1) * CC + cH * 64) * CC;
#pragma unroll
            for (int i = 0; i < 4; i++) {
                rh[i] = *(const short8*)(gh + (srow + i * 16) * CC + scol);
                rl[i] = *(const short8*)(gl + (srow + i * 16) * CC + scol);
            }
        }

        const int ky = kk / 3, kx = kk % 3;
        const size_t aoff = ((size_t)(b * 18 + ya + ky) * 18 + (xa + kx)) * CC + quad * 8;
#pragma unroll
        for (int i2 = 0; i2 < 2; i2++) {
            const int cic = kh * 2 + i2;
            short8 ah = *(const short8*)(hhi + aoff + cic * 32);
            short8 al = *(const short8*)(hlo + aoff + cic * 32);
#pragma unroll
            for (int nt = 0; nt < 4; nt++) {
                short8 bh = *(const short8*)&Bsh[(nt * 16 + l15) * CSTR + cic * 32 + quad * 8];
                short8 bl = *(const short8*)&Bsl[(nt * 16 + l15) * CSTR + cic * 32 + quad * 8];
                acc[nt] = __builtin_amdgcn_mfma_f32_16x16x32_bf16(ah, bh, acc[nt], 0, 0, 0);
                acc[nt] = __builtin_amdgcn_mfma_f32_16x16x32_bf16(al, bh, acc[nt], 0, 0, 0);
                acc[nt] = __builtin_amdgcn_mfma_f32_16x16x32_bf16(ah, bl, acc[nt], 0, 0, 0);
            }
        }
    }

    __syncthreads();
    if (kh == 1) {
#pragma unroll
        for (int nt = 0; nt < 4; nt++)
#pragma unroll
            for (int r = 0; r < 4; r++)
                red[pxg][quad * 4 + r][nt * 16 + l15] = acc[nt][r];
    }
    __syncthreads();

    if (kh == 0) {
        const int pe = pxbase + pxg * 16 + quad * 4;
        float lsum = 0.f;
#pragma unroll
        for (int nt = 0; nt < 4; nt++) {
            int cout = cH * 64 + nt * 16 + l15;
            float bias = pb[kphi * CC + cout];
            size_t gi = ((size_t)b * CC + cout) * 256 + pe;
            float4 h4  = *(const float4*)(hfp + gi);
            float4 f4  = *(const float4*)(f + gi);
            float4 fh4 = FIRST ? make_float4(0.f, 0.f, 0.f, 0.f) : *(const float4*)(f_hat + gi);
            float c0 = acc[nt][0] + red[pxg][quad * 4 + 0][nt * 16 + l15] + bias;
            float c1 = acc[nt][1] + red[pxg][quad * 4 + 1][nt * 16 + l15] + bias;
            float c2 = acc[nt][2] + red[pxg][quad * 4 + 2][nt * 16 + l15] + bias;
            float c3 = acc[nt][3] + red[pxg][quad * 4 + 3][nt * 16 + l15] + bias;
            float o0 = fh4.x + 0.5f * h4.x + 0.5f * c0;
            float o1 = fh4.y + 0.5f * h4.y + 0.5f * c1;
            float o2 = fh4.z + 0.5f * h4.z + 0.5f * c2;
            float o3 = fh4.w + 0.5f * h4.w + 0.5f * c3;
            *(float4*)(f_hat + gi) = make_float4(o0, o1, o2, o3);
            float d0 = o0 - f4.x, d1 = o1 - f4.y, d2 = o2 - f4.z, d3 = o3 - f4.w;
            lsum += d0*d0 + d1*d1 + d2*d2 + d3*d3;
        }
#pragma unroll
        for (int off = 32; off; off >>= 1) lsum += __shfl_down(lsum, off, 64);
        if (lane == 0) lred[pxg] = lsum;
    }
    __syncthreads();
    if (t == 0) atomicAdd(lacc, lred[0] + lred[1]);
}

__global__ void finalize_kernel(const float* __restrict__ lacc, float* __restrict__ out_loss) {
    *out_loss = lacc[0] * (0.25f / (float)NELEM);   // (1+BETA)/SN * sum of means
}

extern "C" void kernel_launch(void* const* d_in, const int* in_sizes, int n_in,
                              void* d_out, int out_size, void* d_ws, size_t ws_size,
                              hipStream_t stream) {
    const float* f   = (const float*)d_in[0];
    const float* emb = (const float*)d_in[1];
    const float* pw  = (const float*)d_in[2];
    const float* pb  = (const float*)d_in[3];
    float* out = (float*)d_out;

    uint32_t* w32 = (uint32_t*)d_ws;
    short* rphi = (short*)(w32);                    // 1,048,576 shorts
    short* rplo = (short*)(w32 + 524288);
    short* ephi = (short*)(w32 + 1048576);          // 1,048,576 shorts
    short* eplo = (short*)(w32 + 1572864);
    short* Whi  = (short*)(w32 + 2097152);          // 589,824 shorts
    short* Wlo  = (short*)(w32 + 2392064);
    short* hhi  = (short*)(w32 + 2686976);          // 1,327,104 shorts
    short* hlo  = (short*)(w32 + 3350528);
    float* hfp  = (float*)(w32 + 4014080);          // 1,048,576 f
    float* esq  = (float*)(w32 + 5062656);          // 8192
    float* pbD  = (float*)(w32 + 5070848);          // 262144
    int*   pbI  = (int*)  (w32 + 5332992);          // 262144
    float* lacc = (float*)(w32 + 5595136);          // 1

    // zero halos of h planes (hhi & hlo contiguous)
    hipMemsetAsync(hhi, 0, (size_t)2 * 1327104 * sizeof(short), stream);

    esq_pack<<<512, 256, 0, stream>>>(emb, esq, ephi, eplo, lacc);
    prepack_w<<<256, 256, 0, stream>>>(pw, Whi, Wlo);

    // mirror np.linspace(1/12, 11/12, 4) exactly in float64
    double start = 1.0 / 12.0;
    double stop  = 1.0 - 1.0 / 12.0;
    double step  = (stop - start) / 3.0;
    double ticks[4] = {start, 1.0 * step + start, 2.0 * step + start, stop};

    const int pns[5]    = {1, 2, 4, 8, 16};
    const int qb5[5]    = {1, 1, 4, 16, 64};        // ceil(N/128)
    const int vs5[5]    = {128, 128, 128, 32, 8};   // vslices (x st64 x 64 = 8192)
    const int st5[5]    = {1, 1, 1, 4, 16};         // 64-v steps per block
    const int pgrid5[5] = {1024, 1024, 1024, 1024, 4096};   // pool_pack grids

    for (int si = 0; si < 5; si++) {
        int pn = pns[si];
        int N  = BB * pn * pn;
        double tt = (double)si / 4.0;
        int kphi = 0;
        double bd = fabs(ticks[0] - tt);
        for (int i = 1; i < 4; i++) {
            double d = fabs(ticks[i] - tt);
            if (d < bd) { bd = d; kphi = i; }   // np.argmin: first occurrence
        }

        switch (pn) {
            case 1:  pool_pack<1,  true ><<<pgrid5[si], 256, 0, stream>>>(f, out, rphi, rplo); break;
            case 2:  pool_pack<2,  false><<<pgrid5[si], 256, 0, stream>>>(f, out, rphi, rplo); break;
            case 4:  pool_pack<4,  false><<<pgrid5[si], 256, 0, stream>>>(f, out, rphi, rplo); break;
            case 8:  pool_pack<8,  false><<<pgrid5[si], 256, 0, stream>>>(f, out, rphi, rplo); break;
            default: pool_pack<16, false><<<pgrid5[si], 256, 0, stream>>>(f, out, rphi, rplo); break;
        }

        dim3 dgrid(qb5[si], vs5[si]);
        dist_mfma<<<dgrid, 512, 0, stream>>>(rphi, rplo, ephi, eplo, esq, pbD, pbI, N, st5[si]);

        int vsplit = vs5[si] * 2;
        switch (pn) {
            case 1:  upsample_pack<1><<<512, 256, 0, stream>>>(emb, pbD, pbI, vsplit, hhi, hlo, hfp); break;
            case 2:  upsample_pack<2><<<512, 256, 0, stream>>>(emb, pbD, pbI, vsplit, hhi, hlo, hfp); break;
            case 4:  upsample_pack<4><<<512, 256, 0, stream>>>(emb, pbD, pbI, vsplit, hhi, hlo, hfp); break;
            case 8:  upsample_pack<8><<<512, 256, 0, stream>>>(emb, pbD, pbI, vsplit, hhi, hlo, hfp); break;
            default: upsample_pack<16><<<512, 256, 0, stream>>>(emb, pbD, pbI, vsplit, hhi, hlo, hfp); break;
        }

        if (si == 0) conv_mfma<true><<<512, 256, 0, stream>>>(Whi, Wlo, hhi, hlo, hfp, pb, f, out, lacc, kphi);
        else         conv_mfma<false><<<512, 256, 0, stream>>>(Whi, Wlo, hhi, hlo, hfp, pb, f, out, lacc, kphi);
    }

    finalize_kernel<<<1, 1, 0, stream>>>(lacc, out + NELEM);
}